// Round 5
// baseline (3334.322 us; speedup 1.0000x reference)
//
#include <hip/hip_runtime.h>
#include <stdint.h>

typedef unsigned short u16;
typedef __bf16 bf16x8 __attribute__((ext_vector_type(8)));
typedef float f32x4 __attribute__((ext_vector_type(4)));

#define DEV static __device__ __forceinline__

DEV u16 f2bu(float f) {
    union { float f; unsigned u; } v; v.f = f;
    unsigned r = v.u + 0x7FFFu + ((v.u >> 16) & 1u);
    return (u16)(r >> 16);
}
DEV float b2f(u16 b) {
    union { unsigned u; float f; } v; v.u = ((unsigned)b) << 16;
    return v.f;
}
DEV float fast_tanh(float x) {
    float e = __expf(2.f * x);
    return 1.f - __fdividef(2.f, e + 1.f);
}
DEV float fast_sig(float x) {
    return __fdividef(1.f, 1.f + __expf(-x));
}
DEV void gload_lds(const u16* g, u16* l) {
    __builtin_amdgcn_global_load_lds((const __attribute__((address_space(1))) void*)g,
                                     (__attribute__((address_space(3))) void*)l, 16, 0, 0);
}

// ---------------------------------------------------------------------------
// Generic 128x128 MFMA GEMM (prologue GEMMs), BK=32, 4 waves (2x2).
// ---------------------------------------------------------------------------
template<bool A_F32, bool B_F32, bool B_KXN, bool OUT_BF16, bool BIAS>
__global__ __launch_bounds__(256) void gemm128(
    const void* __restrict__ Ap, int lda,
    const void* __restrict__ Bp, int ldb,
    void* __restrict__ Cp, int ldc,
    const float* __restrict__ bias, int K)
{
    __shared__ u16 As[128 * 40];
    __shared__ u16 Bs[128 * 40];
    const int tid = threadIdx.x;
    const int lane = tid & 63, wave = tid >> 6;
    const int wr = wave >> 1, wc = wave & 1;
    const int m0 = blockIdx.y * 128, n0 = blockIdx.x * 128;

    f32x4 acc[4][4];
#pragma unroll
    for (int m = 0; m < 4; ++m)
#pragma unroll
        for (int n = 0; n < 4; ++n)
            acc[m][n] = (f32x4){0.f, 0.f, 0.f, 0.f};

    for (int k0 = 0; k0 < K; k0 += 32) {
        __syncthreads();
        if (A_F32) {
            const float* A = (const float*)Ap;
#pragma unroll
            for (int i = 0; i < 4; ++i) {
                int c = tid + i * 256;
                int row = c >> 3, kc = (c & 7) * 4;
                float4 v = *(const float4*)&A[(size_t)(m0 + row) * lda + k0 + kc];
                ushort4 o; o.x = f2bu(v.x); o.y = f2bu(v.y); o.z = f2bu(v.z); o.w = f2bu(v.w);
                *(ushort4*)&As[row * 40 + kc] = o;
            }
        } else {
            const u16* A = (const u16*)Ap;
#pragma unroll
            for (int i = 0; i < 2; ++i) {
                int c = tid + i * 256;
                int row = c >> 2, kc = (c & 3) * 8;
                *(int4*)&As[row * 40 + kc] = *(const int4*)&A[(size_t)(m0 + row) * lda + k0 + kc];
            }
        }
        if (B_KXN) {
            const float* B = (const float*)Bp;
#pragma unroll
            for (int i = 0; i < 4; ++i) {
                int c = tid + i * 256;
                int kk = c >> 5, nc = (c & 31) * 4;
                float4 v = *(const float4*)&B[(size_t)(k0 + kk) * ldb + n0 + nc];
                Bs[(nc + 0) * 40 + kk] = f2bu(v.x);
                Bs[(nc + 1) * 40 + kk] = f2bu(v.y);
                Bs[(nc + 2) * 40 + kk] = f2bu(v.z);
                Bs[(nc + 3) * 40 + kk] = f2bu(v.w);
            }
        } else if (B_F32) {
            const float* B = (const float*)Bp;
#pragma unroll
            for (int i = 0; i < 4; ++i) {
                int c = tid + i * 256;
                int row = c >> 3, kc = (c & 7) * 4;
                float4 v = *(const float4*)&B[(size_t)(n0 + row) * ldb + k0 + kc];
                ushort4 o; o.x = f2bu(v.x); o.y = f2bu(v.y); o.z = f2bu(v.z); o.w = f2bu(v.w);
                *(ushort4*)&Bs[row * 40 + kc] = o;
            }
        } else {
            const u16* B = (const u16*)Bp;
#pragma unroll
            for (int i = 0; i < 2; ++i) {
                int c = tid + i * 256;
                int row = c >> 2, kc = (c & 3) * 8;
                *(int4*)&Bs[row * 40 + kc] = *(const int4*)&B[(size_t)(n0 + row) * ldb + k0 + kc];
            }
        }
        __syncthreads();
        const int fr = lane & 15, kq = (lane >> 4) * 8;
        bf16x8 af[4], bq[4];
#pragma unroll
        for (int m = 0; m < 4; ++m)
            af[m] = *(const bf16x8*)&As[(wr * 64 + m * 16 + fr) * 40 + kq];
#pragma unroll
        for (int n = 0; n < 4; ++n)
            bq[n] = *(const bf16x8*)&Bs[(wc * 64 + n * 16 + fr) * 40 + kq];
#pragma unroll
        for (int m = 0; m < 4; ++m)
#pragma unroll
            for (int n = 0; n < 4; ++n)
                acc[m][n] = __builtin_amdgcn_mfma_f32_16x16x32_bf16(af[m], bq[n], acc[m][n], 0, 0, 0);
    }
    const int fr = lane & 15, rq = (lane >> 4) * 4;
#pragma unroll
    for (int m = 0; m < 4; ++m) {
#pragma unroll
        for (int n = 0; n < 4; ++n) {
            int col = n0 + wc * 64 + n * 16 + fr;
            float bv = BIAS ? bias[col] : 0.f;
#pragma unroll
            for (int r = 0; r < 4; ++r) {
                int row = m0 + wr * 64 + m * 16 + rq + r;
                float v = acc[m][n][r] + bv;
                if (OUT_BF16) ((u16*)Cp)[(size_t)row * ldc + col] = f2bu(v);
                else          ((float*)Cp)[(size_t)row * ldc + col] = v;
            }
        }
    }
}

// ---------------------------------------------------------------------------
// Head GEMM: C[2048][32000] = A(bf16 [2048][1024]) @ B(bf16 [32000][1024])^T
// Nontemporal C stores keep the A panel L2-resident.
// ---------------------------------------------------------------------------
__global__ __launch_bounds__(256) void gemm_head(const u16* __restrict__ A,
                                                 const u16* __restrict__ B,
                                                 float* __restrict__ C)
{
    __shared__ u16 As[128 * 32];
    __shared__ u16 Bs[128 * 32];
    const int tid = threadIdx.x, lane = tid & 63, wave = tid >> 6;
    const int wr = wave >> 1, wc = wave & 1;
    int bid = blockIdx.x;                       // 4000 = 8 * 500
    int nb = (bid & 7) * 500 + (bid >> 3);      // XCD-chunked
    const int m0 = (nb & 15) * 128;             // m fastest -> B-panel L2 reuse
    const int n0 = (nb >> 4) * 128;

    f32x4 acc[4][4];
#pragma unroll
    for (int m = 0; m < 4; ++m)
#pragma unroll
        for (int n = 0; n < 4; ++n)
            acc[m][n] = (f32x4){0.f, 0.f, 0.f, 0.f};

    const int srow = lane >> 2;
    const int sk = (lane & 3) * 8;
    const int fr = lane & 15, kq = (lane >> 4) * 8;

    for (int k0 = 0; k0 < 1024; k0 += 32) {
        __syncthreads();
#pragma unroll
        for (int j = 0; j < 2; ++j) {
            const int rb = (j * 4 + wave) * 16;
            gload_lds(&A[(size_t)(m0 + rb + srow) * 1024 + k0 + sk], &As[rb * 32]);
            gload_lds(&B[(size_t)(n0 + rb + srow) * 1024 + k0 + sk], &Bs[rb * 32]);
        }
        __syncthreads();
        bf16x8 af[4], bq[4];
#pragma unroll
        for (int m = 0; m < 4; ++m)
            af[m] = *(const bf16x8*)&As[(wr * 64 + m * 16 + fr) * 32 + kq];
#pragma unroll
        for (int n = 0; n < 4; ++n)
            bq[n] = *(const bf16x8*)&Bs[(wc * 64 + n * 16 + fr) * 32 + kq];
#pragma unroll
        for (int m = 0; m < 4; ++m)
#pragma unroll
            for (int n = 0; n < 4; ++n)
                acc[m][n] = __builtin_amdgcn_mfma_f32_16x16x32_bf16(af[m], bq[n], acc[m][n], 0, 0, 0);
    }
    const int rq = (lane >> 4) * 4;
#pragma unroll
    for (int m = 0; m < 4; ++m)
#pragma unroll
        for (int n = 0; n < 4; ++n) {
            int col = n0 + wc * 64 + n * 16 + fr;
#pragma unroll
            for (int r = 0; r < 4; ++r)
                __builtin_nontemporal_store(acc[m][n][r],
                    &C[(size_t)(m0 + wr * 64 + m * 16 + rq + r) * 32000 + col]);
        }
}

// ---------------------------------------------------------------------------
// Prologue kernels
// ---------------------------------------------------------------------------
__global__ __launch_bounds__(256) void cvt_bf16(const float* __restrict__ in, u16* __restrict__ out)
{
    int i = blockIdx.x * 256 + threadIdx.x;
    float4 v = ((const float4*)in)[i];
    ushort4 o; o.x = f2bu(v.x); o.y = f2bu(v.y); o.z = f2bu(v.z); o.w = f2bu(v.w);
    ((ushort4*)out)[i] = o;
}

// WhidP[(k>>3)][a][k&7] = bf16(W_hid[a][k]) — k-packed for coalesced ph loads
__global__ __launch_bounds__(256) void pack_whid(const float* __restrict__ W, u16* __restrict__ P)
{
    int id = blockIdx.x * 256 + threadIdx.x;   // 262144
    int a = id >> 10, k = id & 1023;
    P[(size_t)(k >> 3) * 2048 + a * 8 + (k & 7)] = f2bu(W[(size_t)a * 1024 + k]);
}

// mean over n of img_bf
__global__ __launch_bounds__(256) void mean_k(const u16* __restrict__ img_bf, float* __restrict__ gT)
{
    int id = blockIdx.x * 256 + threadIdx.x;   // 65536 = 64 b * 1024
    int b = id >> 10;
    int d = (id & 1023) * 2;
    const u16* base = img_bf + (size_t)b * 196 * 2048 + d;
    float s0 = 0.f, s1 = 0.f;
#pragma unroll 4
    for (int n = 0; n < 196; ++n) {
        ushort2 v = *(const ushort2*)(base + (size_t)n * 2048);
        s0 += b2f(v.x);
        s1 += b2f(v.y);
    }
    gT[(d + 0) * 64 + b] = s0 * (1.f / 196.f);
    gT[(d + 1) * 64 + b] = s1 * (1.f / 196.f);
}

// emb_bf[t*64+b][e] (note [t][b] row order)
__global__ __launch_bounds__(256) void emb_gather(const int* __restrict__ tok,
                                                  const float* __restrict__ embed,
                                                  u16* __restrict__ emb_bf)
{
    int id = blockIdx.x * 256 + threadIdx.x;
    int row = id >> 9, e = id & 511;
    int t = row >> 6, b = row & 63;
    int tk = tok[b * 32 + t];
    emb_bf[(size_t)row * 512 + e] = f2bu(embed[(size_t)tk * 512 + e]);
}

__global__ __launch_bounds__(256) void bias_sum(const float* __restrict__ a, const float* __restrict__ b,
                                                float* __restrict__ o)
{
    int i = blockIdx.x * 256 + threadIdx.x;
    o[i] = a[i] + b[i];
}

__global__ __launch_bounds__(256) void h0c0(const float* __restrict__ gT,
                                            const float* __restrict__ Wh0, const float* __restrict__ bh0,
                                            const float* __restrict__ Wc0, const float* __restrict__ bc0,
                                            float* __restrict__ c, u16* __restrict__ h0)
{
    int id = blockIdx.x * 256 + threadIdx.x;
    int b = id & 63, n = id >> 6;
    const float4* Wh = (const float4*)&Wh0[(size_t)n * 2048];
    const float4* Wc = (const float4*)&Wc0[(size_t)n * 2048];
    float s0 = 0.f, s1 = 0.f;
#pragma unroll 4
    for (int k4 = 0; k4 < 512; ++k4) {
        float4 wh = Wh[k4], wc = Wc[k4];
        float g0 = gT[(k4 * 4 + 0) * 64 + b];
        float g1 = gT[(k4 * 4 + 1) * 64 + b];
        float g2 = gT[(k4 * 4 + 2) * 64 + b];
        float g3 = gT[(k4 * 4 + 3) * 64 + b];
        s0 += wh.x * g0 + wh.y * g1 + wh.z * g2 + wh.w * g3;
        s1 += wc.x * g0 + wc.y * g1 + wc.z * g2 + wc.w * g3;
    }
    c[b * 1024 + n] = fast_tanh(s1 + bc0[n]);
    h0[(size_t)b * 1024 + n] = f2bu(fast_tanh(s0 + bh0[n]));
}

// ---------------------------------------------------------------------------
// Per-step kernel 1: ph + scores + softmax + ctx quarter. grid 256 = (b, q).
// ph computed redundantly per block from k-packed WhidP (coalesced).
// ---------------------------------------------------------------------------
__global__ __launch_bounds__(256) void attn2(const u16* __restrict__ hb,      // [64][1024]
                                             const u16* __restrict__ WhidP,   // [128][256][8]
                                             const float* __restrict__ w_score,
                                             const u16* __restrict__ proj_bf, // [64*196][256]
                                             const u16* __restrict__ img_bf,  // [64][196][2048]
                                             u16* __restrict__ ctx_bf)        // [64][2048]
{
    const int b = blockIdx.x >> 2, q = blockIdx.x & 3;
    const int tid = threadIdx.x, lane = tid & 63, wave = tid >> 6;
    __shared__ float ph[256], sc[256], red[256], ws[256];
    __shared__ union { float hsh[1024]; float part[4][512]; } u;

    ws[tid] = w_score[tid];
    sc[tid] = -1e30f;
    {
        ushort4 hv = *(const ushort4*)&hb[(size_t)b * 1024 + tid * 4];
        u.hsh[tid * 4 + 0] = b2f(hv.x);
        u.hsh[tid * 4 + 1] = b2f(hv.y);
        u.hsh[tid * 4 + 2] = b2f(hv.z);
        u.hsh[tid * 4 + 3] = b2f(hv.w);
    }
    __syncthreads();

    // ph[a] = dot(h_b, W_hid[a]); thread a, coalesced k-packed loads
    {
        float s = 0.f;
        const u16* wp = WhidP + tid * 8;
#pragma unroll 8
        for (int kb = 0; kb < 128; ++kb) {
            bf16x8 wv = *(const bf16x8*)(wp + (size_t)kb * 2048);
            const float* hk = &u.hsh[kb * 8];
#pragma unroll
            for (int i = 0; i < 8; ++i) s += hk[i] * (float)wv[i];
        }
        ph[tid] = s;
    }
    __syncthreads();

    // scores: wave w handles n = w, w+4, ...
    for (int n = wave; n < 196; n += 4) {
        const int a0 = lane * 4;
        ushort4 pv = *(const ushort4*)&proj_bf[((size_t)b * 196 + n) * 256 + a0];
        float s = ws[a0 + 0] * fast_tanh(b2f(pv.x) + ph[a0 + 0])
                + ws[a0 + 1] * fast_tanh(b2f(pv.y) + ph[a0 + 1])
                + ws[a0 + 2] * fast_tanh(b2f(pv.z) + ph[a0 + 2])
                + ws[a0 + 3] * fast_tanh(b2f(pv.w) + ph[a0 + 3]);
#pragma unroll
        for (int off = 32; off; off >>= 1) s += __shfl_xor(s, off, 64);
        if (lane == 0) sc[n] = s;
    }
    __syncthreads();

    // softmax over 196 (padded with -1e30)
    red[tid] = sc[tid];
    __syncthreads();
#pragma unroll
    for (int s2 = 128; s2 > 0; s2 >>= 1) {
        if (tid < s2) red[tid] = fmaxf(red[tid], red[tid + s2]);
        __syncthreads();
    }
    const float mx = red[0];
    __syncthreads();
    float e = (tid < 196) ? __expf(sc[tid] - mx) : 0.f;
    red[tid] = e;
    __syncthreads();
#pragma unroll
    for (int s2 = 128; s2 > 0; s2 >>= 1) {
        if (tid < s2) red[tid] += red[tid + s2];
        __syncthreads();
    }
    const float inv = __fdividef(1.f, red[0]);
    __syncthreads();
    sc[tid] = e * inv;
    __syncthreads();

    // ctx quarter: 512 cols; group gid handles 8 cols, 4-way n-split
    const int gid = tid >> 2, st = tid & 3;
    const int c0 = q * 512 + gid * 8;
    const u16* base = img_bf + ((size_t)b * 196) * 2048 + c0;
    float a[8];
#pragma unroll
    for (int i = 0; i < 8; ++i) a[i] = 0.f;
    for (int n = st; n < 196; n += 4) {
        bf16x8 v = *(const bf16x8*)(base + (size_t)n * 2048);
        float wgt = sc[n];
#pragma unroll
        for (int i = 0; i < 8; ++i) a[i] += wgt * (float)v[i];
    }
#pragma unroll
    for (int i = 0; i < 8; ++i) u.part[st][gid * 8 + i] = a[i];
    __syncthreads();
    const int col = tid * 2;
    float v0 = u.part[0][col] + u.part[1][col] + u.part[2][col] + u.part[3][col];
    float v1 = u.part[0][col + 1] + u.part[1][col + 1] + u.part[2][col + 1] + u.part[3][col + 1];
    ushort2 o; o.x = f2bu(v0); o.y = f2bu(v1);
    *(ushort2*)&ctx_bf[(size_t)b * 2048 + q * 512 + col] = o;
}

// ---------------------------------------------------------------------------
// Per-step kernel 2: gates MFMA + LSTM pointwise. grid 256 x 512 threads.
// 8 waves K-split (384 each over K=3072), LDS reduce, fused pointwise.
// ---------------------------------------------------------------------------
__global__ __launch_bounds__(512) void gates_k(const u16* __restrict__ ctx_bf,  // [64][2048]
                                               const u16* __restrict__ hb,      // [64][1024]
                                               const u16* __restrict__ Wic,     // [4096][2048]
                                               const u16* __restrict__ Whh_bf,  // [4096][1024]
                                               const float* __restrict__ xg,    // [32][64][4096]
                                               float* __restrict__ cbuf,        // [64][1024]
                                               u16* __restrict__ h_nxt,         // [64][1024]
                                               u16* __restrict__ h_all,         // [2048][1024]
                                               int t)
{
    const int tid = threadIdx.x, lane = tid & 63, wave = tid >> 6;  // wave 0..7
    const int fr = lane & 15, kq = (lane >> 4) * 8, rq = (lane >> 4) * 4;
    const int hc0 = blockIdx.x * 4;
    const int grow = ((fr >> 2) << 10) + hc0 + (fr & 3);
    const u16* WicR = Wic + (size_t)grow * 2048;
    const u16* WhhR = Whh_bf + (size_t)grow * 1024;
    __shared__ float red[8][64][16];

    f32x4 acc[4];
#pragma unroll
    for (int m = 0; m < 4; ++m) acc[m] = (f32x4){0.f, 0.f, 0.f, 0.f};

    // K in [wave*384, wave*384+384): ctx region [0,2048), h region [2048,3072)
    const int kbeg = wave * 384, kend = kbeg + 384;
    const int cend = kend < 2048 ? kend : 2048;
#pragma unroll 4
    for (int k0 = kbeg; k0 < cend; k0 += 32) {
        bf16x8 bq = *(const bf16x8*)&WicR[k0 + kq];
#pragma unroll
        for (int m = 0; m < 4; ++m) {
            bf16x8 af = *(const bf16x8*)&ctx_bf[(size_t)(m * 16 + fr) * 2048 + k0 + kq];
            acc[m] = __builtin_amdgcn_mfma_f32_16x16x32_bf16(af, bq, acc[m], 0, 0, 0);
        }
    }
    const int hbeg = kbeg > 2048 ? kbeg - 2048 : 0;
    const int hend = kend > 2048 ? kend - 2048 : 0;
#pragma unroll 4
    for (int kh = hbeg; kh < hend; kh += 32) {
        bf16x8 bq = *(const bf16x8*)&WhhR[kh + kq];
#pragma unroll
        for (int m = 0; m < 4; ++m) {
            bf16x8 af = *(const bf16x8*)&hb[(size_t)(m * 16 + fr) * 1024 + kh + kq];
            acc[m] = __builtin_amdgcn_mfma_f32_16x16x32_bf16(af, bq, acc[m], 0, 0, 0);
        }
    }
#pragma unroll
    for (int m = 0; m < 4; ++m)
#pragma unroll
        for (int r = 0; r < 4; ++r)
            red[wave][m * 16 + rq + r][fr] = acc[m][r];
    __syncthreads();

    // pointwise: thread = (batch bb, col j), tid < 256
    if (tid < 256) {
        const int bb = tid >> 2, j = tid & 3;
        const int col = hc0 + j;
        float G[4];
#pragma unroll
        for (int g = 0; g < 4; ++g) {
            const int f2 = g * 4 + j;
            float s = 0.f;
#pragma unroll
            for (int w8 = 0; w8 < 8; ++w8) s += red[w8][bb][f2];
            G[g] = s + xg[((size_t)t * 64 + bb) * 4096 + g * 1024 + col];
        }
        float ig = fast_sig(G[0]), fg = fast_sig(G[1]);
        float gv = fast_tanh(G[2]), og = fast_sig(G[3]);
        float cp = cbuf[bb * 1024 + col];
        float cn = fg * cp + ig * gv;
        cbuf[bb * 1024 + col] = cn;
        u16 hv = f2bu(og * fast_tanh(cn));
        h_nxt[(size_t)bb * 1024 + col] = hv;
        h_all[((size_t)bb * 32 + t) * 1024 + col] = hv;
    }
}

// ---------------------------------------------------------------------------
extern "C" void kernel_launch(void* const* d_in, const int* in_sizes, int n_in,
                              void* d_out, int out_size, void* d_ws, size_t ws_size,
                              hipStream_t stream)
{
    const float* img     = (const float*)d_in[0];
    const int*   tok     = (const int*)d_in[1];
    const float* embed   = (const float*)d_in[2];
    const float* W_head1 = (const float*)d_in[3];
    const float* W_ih    = (const float*)d_in[4];
    const float* W_hh    = (const float*)d_in[5];
    const float* b_ih    = (const float*)d_in[6];
    const float* b_hh    = (const float*)d_in[7];
    const float* W_head  = (const float*)d_in[8];
    const float* W_img   = (const float*)d_in[9];
    const float* W_hid   = (const float*)d_in[10];
    const float* w_score = (const float*)d_in[11];
    const float* W_h0    = (const float*)d_in[12];
    const float* b_h0    = (const float*)d_in[13];
    const float* W_c0    = (const float*)d_in[14];
    const float* b_c0    = (const float*)d_in[15];
    float* out = (float*)d_out;

    char* w = (char*)d_ws;
    size_t off = 0;
    auto alloc = [&](size_t bytes) { char* p = w + off; off += (bytes + 255) & ~(size_t)255; return p; };

    u16*   Wic      = (u16*)alloc(4096ULL * 2048 * 2);
    u16*   Whh_bf   = (u16*)alloc(4096ULL * 1024 * 2);
    u16*   WhidP    = (u16*)alloc(256ULL * 1024 * 2);
    u16*   Whead_bf = (u16*)alloc(32000ULL * 1024 * 2);
    u16*   img_bf   = (u16*)alloc(64ULL * 196 * 2048 * 2);
    float* xg       = (float*)alloc(2048ULL * 4096 * 4);
    u16*   proj_bf  = (u16*)alloc(64ULL * 196 * 256 * 2);
    u16*   emb_bf   = (u16*)alloc(2048ULL * 512 * 2);
    u16*   xe       = (u16*)alloc(2048ULL * 512 * 2);
    float* gT       = (float*)alloc(2048ULL * 64 * 4);
    float* cbuf     = (float*)alloc(64ULL * 1024 * 4);
    u16*   hbuf     = (u16*)alloc(2ULL * 64 * 1024 * 2);
    u16*   ctx_bf   = (u16*)alloc(64ULL * 2048 * 2);
    u16*   h_all    = (u16*)alloc(2048ULL * 1024 * 2);
    float* bsum     = (float*)alloc(4096ULL * 4);
    (void)ws_size; (void)in_sizes; (void)n_in; (void)out_size;

    // ---- prologue
    cvt_bf16<<<dim3(25088), dim3(256), 0, stream>>>(img, img_bf);
    cvt_bf16<<<dim3(4096), dim3(256), 0, stream>>>(W_hh, Whh_bf);
    cvt_bf16<<<dim3(32000), dim3(256), 0, stream>>>(W_head, Whead_bf);
    pack_whid<<<dim3(1024), dim3(256), 0, stream>>>(W_hid, WhidP);
    mean_k<<<dim3(256), dim3(256), 0, stream>>>(img_bf, gT);
    emb_gather<<<dim3(4096), dim3(256), 0, stream>>>(tok, embed, emb_bf);
    bias_sum<<<dim3(16), dim3(256), 0, stream>>>(b_ih, b_hh, bsum);
    h0c0<<<dim3(256), dim3(256), 0, stream>>>(gT, W_h0, b_h0, W_c0, b_c0, cbuf, hbuf);

    // xe = emb @ Wa^T (Wa = W_head1[:, :512]); rows ordered [t][b]
    gemm128<false, true, false, true, false><<<dim3(4, 16), dim3(256), 0, stream>>>(
        emb_bf, 512, W_head1, 2560, xe, 512, nullptr, 512);
    // xg = xe @ W_ih^T + (b_ih + b_hh); rows [t][b]
    gemm128<false, true, false, false, true><<<dim3(32, 16), dim3(256), 0, stream>>>(
        xe, 512, W_ih, 512, xg, 4096, bsum, 512);
    // Wic = W_ih @ W_head1[:, 512:]
    gemm128<true, true, true, true, false><<<dim3(16, 32), dim3(256), 0, stream>>>(
        W_ih, 512, W_head1 + 512, 2560, Wic, 2048, nullptr, 512);
    // proj_bf = img_bf @ W_img^T (bf16 output)
    gemm128<false, true, false, true, false><<<dim3(2, 98), dim3(256), 0, stream>>>(
        img_bf, 2048, W_img, 2048, proj_bf, 256, nullptr, 2048);

    // ---- recurrence: 2 kernels per step
    for (int t = 0; t < 32; ++t) {
        u16* hb = hbuf + (size_t)(t & 1) * 65536;
        u16* hn = hbuf + (size_t)((t + 1) & 1) * 65536;
        attn2<<<dim3(256), dim3(256), 0, stream>>>(hb, WhidP, w_score, proj_bf, img_bf, ctx_bf);
        gates_k<<<dim3(256), dim3(512), 0, stream>>>(ctx_bf, hb, Wic, Whh_bf, xg,
                                                     cbuf, hn, h_all, t);
    }

    // ---- logits: out = h_all @ W_head^T
    gemm_head<<<dim3(4000), dim3(256), 0, stream>>>(h_all, Whead_bf, out);
}

// Round 6
// 3005.439 us; speedup vs baseline: 1.1094x; 1.1094x over previous
//
#include <hip/hip_runtime.h>
#include <stdint.h>

typedef unsigned short u16;
typedef __bf16 bf16x8 __attribute__((ext_vector_type(8)));
typedef float f32x4 __attribute__((ext_vector_type(4)));

#define DEV static __device__ __forceinline__

DEV u16 f2bu(float f) {
    union { float f; unsigned u; } v; v.f = f;
    unsigned r = v.u + 0x7FFFu + ((v.u >> 16) & 1u);
    return (u16)(r >> 16);
}
DEV float b2f(u16 b) {
    union { unsigned u; float f; } v; v.u = ((unsigned)b) << 16;
    return v.f;
}
DEV float fast_tanh(float x) {
    float e = __expf(2.f * x);
    return 1.f - __fdividef(2.f, e + 1.f);
}
DEV float fast_sig(float x) {
    return __fdividef(1.f, 1.f + __expf(-x));
}
DEV void gload_lds(const u16* g, u16* l) {
    __builtin_amdgcn_global_load_lds((const __attribute__((address_space(1))) void*)g,
                                     (__attribute__((address_space(3))) void*)l, 16, 0, 0);
}

// ---------------------------------------------------------------------------
// Generic 128x128 MFMA GEMM (prologue GEMMs), BK=32, 4 waves (2x2).
// ---------------------------------------------------------------------------
template<bool A_F32, bool B_F32, bool B_KXN, bool OUT_BF16, bool BIAS>
__global__ __launch_bounds__(256) void gemm128(
    const void* __restrict__ Ap, int lda,
    const void* __restrict__ Bp, int ldb,
    void* __restrict__ Cp, int ldc,
    const float* __restrict__ bias, int K)
{
    __shared__ u16 As[128 * 40];
    __shared__ u16 Bs[128 * 40];
    const int tid = threadIdx.x;
    const int lane = tid & 63, wave = tid >> 6;
    const int wr = wave >> 1, wc = wave & 1;
    const int m0 = blockIdx.y * 128, n0 = blockIdx.x * 128;

    f32x4 acc[4][4];
#pragma unroll
    for (int m = 0; m < 4; ++m)
#pragma unroll
        for (int n = 0; n < 4; ++n)
            acc[m][n] = (f32x4){0.f, 0.f, 0.f, 0.f};

    for (int k0 = 0; k0 < K; k0 += 32) {
        __syncthreads();
        if (A_F32) {
            const float* A = (const float*)Ap;
#pragma unroll
            for (int i = 0; i < 4; ++i) {
                int c = tid + i * 256;
                int row = c >> 3, kc = (c & 7) * 4;
                float4 v = *(const float4*)&A[(size_t)(m0 + row) * lda + k0 + kc];
                ushort4 o; o.x = f2bu(v.x); o.y = f2bu(v.y); o.z = f2bu(v.z); o.w = f2bu(v.w);
                *(ushort4*)&As[row * 40 + kc] = o;
            }
        } else {
            const u16* A = (const u16*)Ap;
#pragma unroll
            for (int i = 0; i < 2; ++i) {
                int c = tid + i * 256;
                int row = c >> 2, kc = (c & 3) * 8;
                *(int4*)&As[row * 40 + kc] = *(const int4*)&A[(size_t)(m0 + row) * lda + k0 + kc];
            }
        }
        if (B_KXN) {
            const float* B = (const float*)Bp;
#pragma unroll
            for (int i = 0; i < 4; ++i) {
                int c = tid + i * 256;
                int kk = c >> 5, nc = (c & 31) * 4;
                float4 v = *(const float4*)&B[(size_t)(k0 + kk) * ldb + n0 + nc];
                Bs[(nc + 0) * 40 + kk] = f2bu(v.x);
                Bs[(nc + 1) * 40 + kk] = f2bu(v.y);
                Bs[(nc + 2) * 40 + kk] = f2bu(v.z);
                Bs[(nc + 3) * 40 + kk] = f2bu(v.w);
            }
        } else if (B_F32) {
            const float* B = (const float*)Bp;
#pragma unroll
            for (int i = 0; i < 4; ++i) {
                int c = tid + i * 256;
                int row = c >> 3, kc = (c & 7) * 4;
                float4 v = *(const float4*)&B[(size_t)(n0 + row) * ldb + k0 + kc];
                ushort4 o; o.x = f2bu(v.x); o.y = f2bu(v.y); o.z = f2bu(v.z); o.w = f2bu(v.w);
                *(ushort4*)&Bs[row * 40 + kc] = o;
            }
        } else {
            const u16* B = (const u16*)Bp;
#pragma unroll
            for (int i = 0; i < 2; ++i) {
                int c = tid + i * 256;
                int row = c >> 2, kc = (c & 3) * 8;
                *(int4*)&Bs[row * 40 + kc] = *(const int4*)&B[(size_t)(n0 + row) * ldb + k0 + kc];
            }
        }
        __syncthreads();
        const int fr = lane & 15, kq = (lane >> 4) * 8;
        bf16x8 af[4], bq[4];
#pragma unroll
        for (int m = 0; m < 4; ++m)
            af[m] = *(const bf16x8*)&As[(wr * 64 + m * 16 + fr) * 40 + kq];
#pragma unroll
        for (int n = 0; n < 4; ++n)
            bq[n] = *(const bf16x8*)&Bs[(wc * 64 + n * 16 + fr) * 40 + kq];
#pragma unroll
        for (int m = 0; m < 4; ++m)
#pragma unroll
            for (int n = 0; n < 4; ++n)
                acc[m][n] = __builtin_amdgcn_mfma_f32_16x16x32_bf16(af[m], bq[n], acc[m][n], 0, 0, 0);
    }
    const int fr = lane & 15, rq = (lane >> 4) * 4;
#pragma unroll
    for (int m = 0; m < 4; ++m) {
#pragma unroll
        for (int n = 0; n < 4; ++n) {
            int col = n0 + wc * 64 + n * 16 + fr;
            float bv = BIAS ? bias[col] : 0.f;
#pragma unroll
            for (int r = 0; r < 4; ++r) {
                int row = m0 + wr * 64 + m * 16 + rq + r;
                float v = acc[m][n][r] + bv;
                if (OUT_BF16) ((u16*)Cp)[(size_t)row * ldc + col] = f2bu(v);
                else          ((float*)Cp)[(size_t)row * ldc + col] = v;
            }
        }
    }
}

// ---------------------------------------------------------------------------
// Head GEMM: C[2048][32000] = A(bf16 [2048][1024]) @ B(bf16 [32000][1024])^T
// ---------------------------------------------------------------------------
__global__ __launch_bounds__(256) void gemm_head(const u16* __restrict__ A,
                                                 const u16* __restrict__ B,
                                                 float* __restrict__ C)
{
    __shared__ u16 As[128 * 32];
    __shared__ u16 Bs[128 * 32];
    const int tid = threadIdx.x, lane = tid & 63, wave = tid >> 6;
    const int wr = wave >> 1, wc = wave & 1;
    int bid = blockIdx.x;                       // 4000 = 8 * 500
    int nb = (bid & 7) * 500 + (bid >> 3);      // XCD-chunked
    const int m0 = (nb & 15) * 128;             // m fastest -> B-panel L2 reuse
    const int n0 = (nb >> 4) * 128;

    f32x4 acc[4][4];
#pragma unroll
    for (int m = 0; m < 4; ++m)
#pragma unroll
        for (int n = 0; n < 4; ++n)
            acc[m][n] = (f32x4){0.f, 0.f, 0.f, 0.f};

    const int srow = lane >> 2;
    const int sk = (lane & 3) * 8;
    const int fr = lane & 15, kq = (lane >> 4) * 8;

    for (int k0 = 0; k0 < 1024; k0 += 32) {
        __syncthreads();
#pragma unroll
        for (int j = 0; j < 2; ++j) {
            const int rb = (j * 4 + wave) * 16;
            gload_lds(&A[(size_t)(m0 + rb + srow) * 1024 + k0 + sk], &As[rb * 32]);
            gload_lds(&B[(size_t)(n0 + rb + srow) * 1024 + k0 + sk], &Bs[rb * 32]);
        }
        __syncthreads();
        bf16x8 af[4], bq[4];
#pragma unroll
        for (int m = 0; m < 4; ++m)
            af[m] = *(const bf16x8*)&As[(wr * 64 + m * 16 + fr) * 32 + kq];
#pragma unroll
        for (int n = 0; n < 4; ++n)
            bq[n] = *(const bf16x8*)&Bs[(wc * 64 + n * 16 + fr) * 32 + kq];
#pragma unroll
        for (int m = 0; m < 4; ++m)
#pragma unroll
            for (int n = 0; n < 4; ++n)
                acc[m][n] = __builtin_amdgcn_mfma_f32_16x16x32_bf16(af[m], bq[n], acc[m][n], 0, 0, 0);
    }
    const int rq = (lane >> 4) * 4;
#pragma unroll
    for (int m = 0; m < 4; ++m)
#pragma unroll
        for (int n = 0; n < 4; ++n) {
            int col = n0 + wc * 64 + n * 16 + fr;
#pragma unroll
            for (int r = 0; r < 4; ++r)
                C[(size_t)(m0 + wr * 64 + m * 16 + rq + r) * 32000 + col] = acc[m][n][r];
        }
}

// ---------------------------------------------------------------------------
// Prologue kernels
// ---------------------------------------------------------------------------
__global__ __launch_bounds__(256) void cvt_bf16(const float* __restrict__ in, u16* __restrict__ out)
{
    int i = blockIdx.x * 256 + threadIdx.x;
    float4 v = ((const float4*)in)[i];
    ushort4 o; o.x = f2bu(v.x); o.y = f2bu(v.y); o.z = f2bu(v.z); o.w = f2bu(v.w);
    ((ushort4*)out)[i] = o;
}

// Fragment-pack gates weights: Wpk[bid][i][lane][8], i = K-iter (0..95),
// value = W[grow(fr)][i*32 + kq + e] with grow = (fr>>2)*1024 + bid*4 + (fr&3),
// Wic for i*32 < 2048, Whh for the rest. grid (24, 256).
__global__ __launch_bounds__(256) void pack_w(const u16* __restrict__ Wic,
                                              const u16* __restrict__ Whh,
                                              u16* __restrict__ Wpk)
{
    const int bid = blockIdx.y;
    const int t2 = blockIdx.x * 256 + threadIdx.x;   // 6144 = 96*64
    const int i = t2 >> 6, lane = t2 & 63;
    const int fr = lane & 15, kq = (lane >> 4) * 8;
    const int grow = ((fr >> 2) << 10) + bid * 4 + (fr & 3);
    const int k0 = i * 32;
    int4 v;
    if (k0 < 2048) v = *(const int4*)&Wic[(size_t)grow * 2048 + k0 + kq];
    else           v = *(const int4*)&Whh[(size_t)grow * 1024 + (k0 - 2048) + kq];
    *(int4*)&Wpk[((size_t)bid * 6144 + t2) * 8] = v;
}

// mean over n of img_bf
__global__ __launch_bounds__(256) void mean_k(const u16* __restrict__ img_bf, float* __restrict__ gT)
{
    int id = blockIdx.x * 256 + threadIdx.x;   // 65536 = 64 b * 1024
    int b = id >> 10;
    int d = (id & 1023) * 2;
    const u16* base = img_bf + (size_t)b * 196 * 2048 + d;
    float s0 = 0.f, s1 = 0.f;
#pragma unroll 4
    for (int n = 0; n < 196; ++n) {
        ushort2 v = *(const ushort2*)(base + (size_t)n * 2048);
        s0 += b2f(v.x);
        s1 += b2f(v.y);
    }
    gT[(d + 0) * 64 + b] = s0 * (1.f / 196.f);
    gT[(d + 1) * 64 + b] = s1 * (1.f / 196.f);
}

// emb_bf[t*64+b][e] ([t][b] row order)
__global__ __launch_bounds__(256) void emb_gather(const int* __restrict__ tok,
                                                  const float* __restrict__ embed,
                                                  u16* __restrict__ emb_bf)
{
    int id = blockIdx.x * 256 + threadIdx.x;
    int row = id >> 9, e = id & 511;
    int t = row >> 6, b = row & 63;
    int tk = tok[b * 32 + t];
    emb_bf[(size_t)row * 512 + e] = f2bu(embed[(size_t)tk * 512 + e]);
}

__global__ __launch_bounds__(256) void bias_sum(const float* __restrict__ a, const float* __restrict__ b,
                                                float* __restrict__ o)
{
    int i = blockIdx.x * 256 + threadIdx.x;
    o[i] = a[i] + b[i];
}

__global__ __launch_bounds__(256) void h0c0(const float* __restrict__ gT,
                                            const float* __restrict__ Wh0, const float* __restrict__ bh0,
                                            const float* __restrict__ Wc0, const float* __restrict__ bc0,
                                            float* __restrict__ c, u16* __restrict__ h0)
{
    int id = blockIdx.x * 256 + threadIdx.x;
    int b = id & 63, n = id >> 6;
    const float4* Wh = (const float4*)&Wh0[(size_t)n * 2048];
    const float4* Wc = (const float4*)&Wc0[(size_t)n * 2048];
    float s0 = 0.f, s1 = 0.f;
#pragma unroll 4
    for (int k4 = 0; k4 < 512; ++k4) {
        float4 wh = Wh[k4], wc = Wc[k4];
        float g0 = gT[(k4 * 4 + 0) * 64 + b];
        float g1 = gT[(k4 * 4 + 1) * 64 + b];
        float g2 = gT[(k4 * 4 + 2) * 64 + b];
        float g3 = gT[(k4 * 4 + 3) * 64 + b];
        s0 += wh.x * g0 + wh.y * g1 + wh.z * g2 + wh.w * g3;
        s1 += wc.x * g0 + wc.y * g1 + wc.z * g2 + wc.w * g3;
    }
    c[b * 1024 + n] = fast_tanh(s1 + bc0[n]);
    h0[(size_t)b * 1024 + n] = f2bu(fast_tanh(s0 + bh0[n]));
}

// ---------------------------------------------------------------------------
// Per-step kernels (R4 structure)
// ---------------------------------------------------------------------------

// ph_all[b][a] = h @ W_hid^T. grid 16 blocks x 16 a-cols.
__global__ __launch_bounds__(256) void ph_k(const u16* __restrict__ hb,      // [64][1024]
                                            const u16* __restrict__ Whid_bf, // [256][1024]
                                            float* __restrict__ ph_all)      // [64][256]
{
    const int tid = threadIdx.x, lane = tid & 63, wave = tid >> 6;
    const int fr = lane & 15, kq = (lane >> 4) * 8, rq = (lane >> 4) * 4;
    const int a0 = blockIdx.x * 16;
    __shared__ float red[4][64][16];
    f32x4 acc[4];
#pragma unroll
    for (int m = 0; m < 4; ++m) acc[m] = (f32x4){0.f, 0.f, 0.f, 0.f};
#pragma unroll
    for (int kk = 0; kk < 256; kk += 32) {
        const int k0 = wave * 256 + kk;
        bf16x8 bq = *(const bf16x8*)&Whid_bf[(size_t)(a0 + fr) * 1024 + k0 + kq];
#pragma unroll
        for (int m = 0; m < 4; ++m) {
            bf16x8 af = *(const bf16x8*)&hb[(size_t)(m * 16 + fr) * 1024 + k0 + kq];
            acc[m] = __builtin_amdgcn_mfma_f32_16x16x32_bf16(af, bq, acc[m], 0, 0, 0);
        }
    }
#pragma unroll
    for (int m = 0; m < 4; ++m)
#pragma unroll
        for (int r = 0; r < 4; ++r)
            red[wave][m * 16 + rq + r][fr] = acc[m][r];
    __syncthreads();
#pragma unroll
    for (int i = 0; i < 4; ++i) {
        const int idx = tid + i * 256;
        const int bb = idx >> 4, a = idx & 15;
        ph_all[bb * 256 + a0 + a] = red[0][bb][a] + red[1][bb][a] + red[2][bb][a] + red[3][bb][a];
    }
}

// scores + softmax + ctx quarter. grid 256 = (b, d-quarter). proj in bf16.
__global__ __launch_bounds__(256) void attn_k(const float* __restrict__ ph_all,  // [64][256]
                                              const float* __restrict__ w_score, // [256]
                                              const u16* __restrict__ proj_bf,   // [64*196][256]
                                              const u16* __restrict__ img_bf,    // [64][196][2048]
                                              u16* __restrict__ ctx_bf)          // [64][2048]
{
    const int b = blockIdx.x >> 2, q = blockIdx.x & 3;
    const int tid = threadIdx.x, lane = tid & 63, wave = tid >> 6;
    __shared__ float ph[256], ws[256], sc[256], red[256];
    __shared__ float part[4][512];
    ph[tid] = ph_all[b * 256 + tid];
    ws[tid] = w_score[tid];
    sc[tid] = -1e30f;
    __syncthreads();
    // scores: wave w handles n = w, w+4, ...
    for (int n = wave; n < 196; n += 4) {
        const int a0 = lane * 4;
        ushort4 pv = *(const ushort4*)&proj_bf[((size_t)b * 196 + n) * 256 + a0];
        float s = ws[a0 + 0] * fast_tanh(b2f(pv.x) + ph[a0 + 0])
                + ws[a0 + 1] * fast_tanh(b2f(pv.y) + ph[a0 + 1])
                + ws[a0 + 2] * fast_tanh(b2f(pv.z) + ph[a0 + 2])
                + ws[a0 + 3] * fast_tanh(b2f(pv.w) + ph[a0 + 3]);
#pragma unroll
        for (int off = 32; off; off >>= 1) s += __shfl_xor(s, off, 64);
        if (lane == 0) sc[n] = s;
    }
    __syncthreads();
    // softmax over 196 (padded with -1e30)
    red[tid] = sc[tid];
    __syncthreads();
#pragma unroll
    for (int s2 = 128; s2 > 0; s2 >>= 1) {
        if (tid < s2) red[tid] = fmaxf(red[tid], red[tid + s2]);
        __syncthreads();
    }
    const float mx = red[0];
    __syncthreads();
    float e = (tid < 196) ? __expf(sc[tid] - mx) : 0.f;
    red[tid] = e;
    __syncthreads();
#pragma unroll
    for (int s2 = 128; s2 > 0; s2 >>= 1) {
        if (tid < s2) red[tid] += red[tid + s2];
        __syncthreads();
    }
    const float inv = __fdividef(1.f, red[0]);
    __syncthreads();
    sc[tid] = e * inv;
    __syncthreads();
    // ctx quarter: 512 cols; group gid handles 8 cols, 4-way n-split
    const int gid = tid >> 2, st = tid & 3;
    const int c0 = q * 512 + gid * 8;
    const u16* base = img_bf + ((size_t)b * 196) * 2048 + c0;
    float a[8];
#pragma unroll
    for (int i = 0; i < 8; ++i) a[i] = 0.f;
    for (int n = st; n < 196; n += 4) {
        bf16x8 v = *(const bf16x8*)(base + (size_t)n * 2048);
        float wgt = sc[n];
#pragma unroll
        for (int i = 0; i < 8; ++i) a[i] += wgt * (float)v[i];
    }
#pragma unroll
    for (int i = 0; i < 8; ++i) part[st][gid * 8 + i] = a[i];
    __syncthreads();
    const int col = tid * 2;
    float v0 = part[0][col] + part[1][col] + part[2][col] + part[3][col];
    float v1 = part[0][col + 1] + part[1][col + 1] + part[2][col + 1] + part[3][col + 1];
    ushort2 o; o.x = f2bu(v0); o.y = f2bu(v1);
    *(ushort2*)&ctx_bf[(size_t)b * 2048 + q * 512 + col] = o;
}

// gates MFMA + LSTM pointwise. grid 256 x 256 threads, 4-wave K-split (768 each).
// B-operand from fragment-packed Wpk: one coalesced 1KB wave-load per K-iter.
__global__ __launch_bounds__(256) void gates_k(const u16* __restrict__ ctx_bf,  // [64][2048]
                                               const u16* __restrict__ hb,      // [64][1024]
                                               const u16* __restrict__ Wpk,     // [256][96][64][8]
                                               const float* __restrict__ xg,    // [32][64][4096]
                                               float* __restrict__ cbuf,        // [64][1024]
                                               u16* __restrict__ h_nxt,         // [64][1024]
                                               u16* __restrict__ h_all,         // [2048][1024]
                                               int t)
{
    const int tid = threadIdx.x, lane = tid & 63, wave = tid >> 6;
    const int fr = lane & 15, kq = (lane >> 4) * 8, rq = (lane >> 4) * 4;
    const int hc0 = blockIdx.x * 4;
    const u16* Wblk = Wpk + (size_t)blockIdx.x * 49152 + lane * 8;  // [96][64][8]
    __shared__ float red[4][64][16];

    f32x4 acc[4];
#pragma unroll
    for (int m = 0; m < 4; ++m) acc[m] = (f32x4){0.f, 0.f, 0.f, 0.f};

    // K in [wave*768, wave*768+768): ctx region [0,2048), h region [2048,3072)
    const int kbeg = wave * 768, kend = kbeg + 768;
    const int cend = kend < 2048 ? kend : 2048;
#pragma unroll 4
    for (int k0 = kbeg; k0 < cend; k0 += 32) {
        bf16x8 bq = *(const bf16x8*)&Wblk[(size_t)(k0 >> 5) * 512];
#pragma unroll
        for (int m = 0; m < 4; ++m) {
            bf16x8 af = *(const bf16x8*)&ctx_bf[(size_t)(m * 16 + fr) * 2048 + k0 + kq];
            acc[m] = __builtin_amdgcn_mfma_f32_16x16x32_bf16(af, bq, acc[m], 0, 0, 0);
        }
    }
    const int hbeg = kbeg > 2048 ? kbeg - 2048 : 0;
    const int hend = kend > 2048 ? kend - 2048 : 0;
#pragma unroll 4
    for (int kh = hbeg; kh < hend; kh += 32) {
        bf16x8 bq = *(const bf16x8*)&Wblk[(size_t)((kh + 2048) >> 5) * 512];
#pragma unroll
        for (int m = 0; m < 4; ++m) {
            bf16x8 af = *(const bf16x8*)&hb[(size_t)(m * 16 + fr) * 1024 + kh + kq];
            acc[m] = __builtin_amdgcn_mfma_f32_16x16x32_bf16(af, bq, acc[m], 0, 0, 0);
        }
    }
#pragma unroll
    for (int m = 0; m < 4; ++m)
#pragma unroll
        for (int r = 0; r < 4; ++r)
            red[wave][m * 16 + rq + r][fr] = acc[m][r];
    __syncthreads();

    // pointwise: thread = (batch bb, col j)
    const int bb = tid >> 2, j = tid & 3;
    const int col = hc0 + j;
    float G[4];
#pragma unroll
    for (int g = 0; g < 4; ++g) {
        const int f2 = g * 4 + j;
        G[g] = red[0][bb][f2] + red[1][bb][f2] + red[2][bb][f2] + red[3][bb][f2]
             + xg[((size_t)t * 64 + bb) * 4096 + g * 1024 + col];
    }
    float ig = fast_sig(G[0]), fg = fast_sig(G[1]);
    float gv = fast_tanh(G[2]), og = fast_sig(G[3]);
    float cp = cbuf[bb * 1024 + col];
    float cn = fg * cp + ig * gv;
    cbuf[bb * 1024 + col] = cn;
    u16 hv = f2bu(og * fast_tanh(cn));
    h_nxt[(size_t)bb * 1024 + col] = hv;
    h_all[((size_t)bb * 32 + t) * 1024 + col] = hv;
}

// ---------------------------------------------------------------------------
extern "C" void kernel_launch(void* const* d_in, const int* in_sizes, int n_in,
                              void* d_out, int out_size, void* d_ws, size_t ws_size,
                              hipStream_t stream)
{
    const float* img     = (const float*)d_in[0];
    const int*   tok     = (const int*)d_in[1];
    const float* embed   = (const float*)d_in[2];
    const float* W_head1 = (const float*)d_in[3];
    const float* W_ih    = (const float*)d_in[4];
    const float* W_hh    = (const float*)d_in[5];
    const float* b_ih    = (const float*)d_in[6];
    const float* b_hh    = (const float*)d_in[7];
    const float* W_head  = (const float*)d_in[8];
    const float* W_img   = (const float*)d_in[9];
    const float* W_hid   = (const float*)d_in[10];
    const float* w_score = (const float*)d_in[11];
    const float* W_h0    = (const float*)d_in[12];
    const float* b_h0    = (const float*)d_in[13];
    const float* W_c0    = (const float*)d_in[14];
    const float* b_c0    = (const float*)d_in[15];
    float* out = (float*)d_out;

    char* w = (char*)d_ws;
    size_t off = 0;
    auto alloc = [&](size_t bytes) { char* p = w + off; off += (bytes + 255) & ~(size_t)255; return p; };

    u16*   Wic      = (u16*)alloc(4096ULL * 2048 * 2);
    u16*   Whh_bf   = (u16*)alloc(4096ULL * 1024 * 2);
    u16*   Wpk      = (u16*)alloc(256ULL * 96 * 64 * 8 * 2);   // 24 MB fragment-packed
    u16*   Whid_bf  = (u16*)alloc(256ULL * 1024 * 2);
    u16*   Whead_bf = (u16*)alloc(32000ULL * 1024 * 2);
    u16*   img_bf   = (u16*)alloc(64ULL * 196 * 2048 * 2);
    float* xg       = (float*)alloc(2048ULL * 4096 * 4);
    u16*   proj_bf  = (u16*)alloc(64ULL * 196 * 256 * 2);
    u16*   emb_bf   = (u16*)alloc(2048ULL * 512 * 2);
    u16*   xe       = (u16*)alloc(2048ULL * 512 * 2);
    float* gT       = (float*)alloc(2048ULL * 64 * 4);
    float* cbuf     = (float*)alloc(64ULL * 1024 * 4);
    u16*   hbuf     = (u16*)alloc(2ULL * 64 * 1024 * 2);
    u16*   ctx_bf   = (u16*)alloc(64ULL * 2048 * 2);
    u16*   h_all    = (u16*)alloc(2048ULL * 1024 * 2);
    float* ph_all   = (float*)alloc(64ULL * 256 * 4);
    float* bsum     = (float*)alloc(4096ULL * 4);
    (void)ws_size; (void)in_sizes; (void)n_in; (void)out_size;

    // ---- prologue
    cvt_bf16<<<dim3(25088), dim3(256), 0, stream>>>(img, img_bf);
    cvt_bf16<<<dim3(4096), dim3(256), 0, stream>>>(W_hh, Whh_bf);
    cvt_bf16<<<dim3(256), dim3(256), 0, stream>>>(W_hid, Whid_bf);
    cvt_bf16<<<dim3(32000), dim3(256), 0, stream>>>(W_head, Whead_bf);
    mean_k<<<dim3(256), dim3(256), 0, stream>>>(img_bf, gT);
    emb_gather<<<dim3(4096), dim3(256), 0, stream>>>(tok, embed, emb_bf);
    bias_sum<<<dim3(16), dim3(256), 0, stream>>>(b_ih, b_hh, bsum);
    h0c0<<<dim3(256), dim3(256), 0, stream>>>(gT, W_h0, b_h0, W_c0, b_c0, cbuf, hbuf);

    // xe = emb @ Wa^T (Wa = W_head1[:, :512]); rows [t][b]
    gemm128<false, true, false, true, false><<<dim3(4, 16), dim3(256), 0, stream>>>(
        emb_bf, 512, W_head1, 2560, xe, 512, nullptr, 512);
    // xg = xe @ W_ih^T + (b_ih + b_hh); rows [t][b]
    gemm128<false, true, false, false, true><<<dim3(32, 16), dim3(256), 0, stream>>>(
        xe, 512, W_ih, 512, xg, 4096, bsum, 512);
    // Wic = W_ih @ W_head1[:, 512:]
    gemm128<true, true, true, true, false><<<dim3(16, 32), dim3(256), 0, stream>>>(
        W_ih, 512, W_head1 + 512, 2560, Wic, 2048, nullptr, 512);
    // proj_bf = img_bf @ W_img^T (bf16 out)
    gemm128<false, true, false, true, false><<<dim3(2, 98), dim3(256), 0, stream>>>(
        img_bf, 2048, W_img, 2048, proj_bf, 256, nullptr, 2048);
    // fragment-pack gates weights (needs Wic + Whh_bf)
    pack_w<<<dim3(24, 256), dim3(256), 0, stream>>>(Wic, Whh_bf, Wpk);

    // ---- recurrence: 3 kernels per step (R4 structure)
    for (int t = 0; t < 32; ++t) {
        u16* hb = hbuf + (size_t)(t & 1) * 65536;
        u16* hn = hbuf + (size_t)((t + 1) & 1) * 65536;
        ph_k<<<dim3(16), dim3(256), 0, stream>>>(hb, Whid_bf, ph_all);
        attn_k<<<dim3(256), dim3(256), 0, stream>>>(ph_all, w_score, proj_bf, img_bf, ctx_bf);
        gates_k<<<dim3(256), dim3(256), 0, stream>>>(ctx_bf, hb, Wpk, xg, cbuf, hn, h_all, t);
    }

    // ---- logits: out = h_all @ W_head^T
    gemm_head<<<dim3(4000), dim3(256), 0, stream>>>(h_all, Whead_bf, out);
}

// Round 7
// 2291.887 us; speedup vs baseline: 1.4548x; 1.3113x over previous
//
#include <hip/hip_runtime.h>
#include <stdint.h>

typedef unsigned short u16;
typedef __bf16 bf16x8 __attribute__((ext_vector_type(8)));
typedef float f32x4 __attribute__((ext_vector_type(4)));

#define DEV static __device__ __forceinline__

DEV u16 f2bu(float f) {
    union { float f; unsigned u; } v; v.f = f;
    unsigned r = v.u + 0x7FFFu + ((v.u >> 16) & 1u);
    return (u16)(r >> 16);
}
DEV float b2f(u16 b) {
    union { unsigned u; float f; } v; v.u = ((unsigned)b) << 16;
    return v.f;
}
DEV float fast_tanh(float x) {
    float e = __expf(2.f * x);
    return 1.f - __fdividef(2.f, e + 1.f);
}
DEV float fast_sig(float x) {
    return __fdividef(1.f, 1.f + __expf(-x));
}
DEV void gload_lds(const u16* g, u16* l) {
    __builtin_amdgcn_global_load_lds((const __attribute__((address_space(1))) void*)g,
                                     (__attribute__((address_space(3))) void*)l, 16, 0, 0);
}

// ---------------------------------------------------------------------------
// Generic 128x128 MFMA GEMM (prologue GEMMs), BK=32, 4 waves (2x2).
// ---------------------------------------------------------------------------
template<bool A_F32, bool B_F32, bool B_KXN, bool OUT_BF16, bool BIAS>
__global__ __launch_bounds__(256) void gemm128(
    const void* __restrict__ Ap, int lda,
    const void* __restrict__ Bp, int ldb,
    void* __restrict__ Cp, int ldc,
    const float* __restrict__ bias, int K)
{
    __shared__ u16 As[128 * 40];
    __shared__ u16 Bs[128 * 40];
    const int tid = threadIdx.x;
    const int lane = tid & 63, wave = tid >> 6;
    const int wr = wave >> 1, wc = wave & 1;
    const int m0 = blockIdx.y * 128, n0 = blockIdx.x * 128;

    f32x4 acc[4][4];
#pragma unroll
    for (int m = 0; m < 4; ++m)
#pragma unroll
        for (int n = 0; n < 4; ++n)
            acc[m][n] = (f32x4){0.f, 0.f, 0.f, 0.f};

    for (int k0 = 0; k0 < K; k0 += 32) {
        __syncthreads();
        if (A_F32) {
            const float* A = (const float*)Ap;
#pragma unroll
            for (int i = 0; i < 4; ++i) {
                int c = tid + i * 256;
                int row = c >> 3, kc = (c & 7) * 4;
                float4 v = *(const float4*)&A[(size_t)(m0 + row) * lda + k0 + kc];
                ushort4 o; o.x = f2bu(v.x); o.y = f2bu(v.y); o.z = f2bu(v.z); o.w = f2bu(v.w);
                *(ushort4*)&As[row * 40 + kc] = o;
            }
        } else {
            const u16* A = (const u16*)Ap;
#pragma unroll
            for (int i = 0; i < 2; ++i) {
                int c = tid + i * 256;
                int row = c >> 2, kc = (c & 3) * 8;
                *(int4*)&As[row * 40 + kc] = *(const int4*)&A[(size_t)(m0 + row) * lda + k0 + kc];
            }
        }
        if (B_KXN) {
            const float* B = (const float*)Bp;
#pragma unroll
            for (int i = 0; i < 4; ++i) {
                int c = tid + i * 256;
                int kk = c >> 5, nc = (c & 31) * 4;
                float4 v = *(const float4*)&B[(size_t)(k0 + kk) * ldb + n0 + nc];
                Bs[(nc + 0) * 40 + kk] = f2bu(v.x);
                Bs[(nc + 1) * 40 + kk] = f2bu(v.y);
                Bs[(nc + 2) * 40 + kk] = f2bu(v.z);
                Bs[(nc + 3) * 40 + kk] = f2bu(v.w);
            }
        } else if (B_F32) {
            const float* B = (const float*)Bp;
#pragma unroll
            for (int i = 0; i < 4; ++i) {
                int c = tid + i * 256;
                int row = c >> 3, kc = (c & 7) * 4;
                float4 v = *(const float4*)&B[(size_t)(n0 + row) * ldb + k0 + kc];
                ushort4 o; o.x = f2bu(v.x); o.y = f2bu(v.y); o.z = f2bu(v.z); o.w = f2bu(v.w);
                *(ushort4*)&Bs[row * 40 + kc] = o;
            }
        } else {
            const u16* B = (const u16*)Bp;
#pragma unroll
            for (int i = 0; i < 2; ++i) {
                int c = tid + i * 256;
                int row = c >> 2, kc = (c & 3) * 8;
                *(int4*)&Bs[row * 40 + kc] = *(const int4*)&B[(size_t)(n0 + row) * ldb + k0 + kc];
            }
        }
        __syncthreads();
        const int fr = lane & 15, kq = (lane >> 4) * 8;
        bf16x8 af[4], bq[4];
#pragma unroll
        for (int m = 0; m < 4; ++m)
            af[m] = *(const bf16x8*)&As[(wr * 64 + m * 16 + fr) * 40 + kq];
#pragma unroll
        for (int n = 0; n < 4; ++n)
            bq[n] = *(const bf16x8*)&Bs[(wc * 64 + n * 16 + fr) * 40 + kq];
#pragma unroll
        for (int m = 0; m < 4; ++m)
#pragma unroll
            for (int n = 0; n < 4; ++n)
                acc[m][n] = __builtin_amdgcn_mfma_f32_16x16x32_bf16(af[m], bq[n], acc[m][n], 0, 0, 0);
    }
    const int fr = lane & 15, rq = (lane >> 4) * 4;
#pragma unroll
    for (int m = 0; m < 4; ++m) {
#pragma unroll
        for (int n = 0; n < 4; ++n) {
            int col = n0 + wc * 64 + n * 16 + fr;
            float bv = BIAS ? bias[col] : 0.f;
#pragma unroll
            for (int r = 0; r < 4; ++r) {
                int row = m0 + wr * 64 + m * 16 + rq + r;
                float v = acc[m][n][r] + bv;
                if (OUT_BF16) ((u16*)Cp)[(size_t)row * ldc + col] = f2bu(v);
                else          ((float*)Cp)[(size_t)row * ldc + col] = v;
            }
        }
    }
}

// ---------------------------------------------------------------------------
// Head GEMM: C[2048][32000] = A(bf16 [2048][1024]) @ B(bf16 [32000][1024])^T
// ---------------------------------------------------------------------------
__global__ __launch_bounds__(256) void gemm_head(const u16* __restrict__ A,
                                                 const u16* __restrict__ B,
                                                 float* __restrict__ C)
{
    __shared__ u16 As[128 * 32];
    __shared__ u16 Bs[128 * 32];
    const int tid = threadIdx.x, lane = tid & 63, wave = tid >> 6;
    const int wr = wave >> 1, wc = wave & 1;
    int bid = blockIdx.x;                       // 4000 = 8 * 500
    int nb = (bid & 7) * 500 + (bid >> 3);      // XCD-chunked
    const int m0 = (nb & 15) * 128;             // m fastest -> B-panel L2 reuse
    const int n0 = (nb >> 4) * 128;

    f32x4 acc[4][4];
#pragma unroll
    for (int m = 0; m < 4; ++m)
#pragma unroll
        for (int n = 0; n < 4; ++n)
            acc[m][n] = (f32x4){0.f, 0.f, 0.f, 0.f};

    const int srow = lane >> 2;
    const int sk = (lane & 3) * 8;
    const int fr = lane & 15, kq = (lane >> 4) * 8;

    for (int k0 = 0; k0 < 1024; k0 += 32) {
        __syncthreads();
#pragma unroll
        for (int j = 0; j < 2; ++j) {
            const int rb = (j * 4 + wave) * 16;
            gload_lds(&A[(size_t)(m0 + rb + srow) * 1024 + k0 + sk], &As[rb * 32]);
            gload_lds(&B[(size_t)(n0 + rb + srow) * 1024 + k0 + sk], &Bs[rb * 32]);
        }
        __syncthreads();
        bf16x8 af[4], bq[4];
#pragma unroll
        for (int m = 0; m < 4; ++m)
            af[m] = *(const bf16x8*)&As[(wr * 64 + m * 16 + fr) * 32 + kq];
#pragma unroll
        for (int n = 0; n < 4; ++n)
            bq[n] = *(const bf16x8*)&Bs[(wc * 64 + n * 16 + fr) * 32 + kq];
#pragma unroll
        for (int m = 0; m < 4; ++m)
#pragma unroll
            for (int n = 0; n < 4; ++n)
                acc[m][n] = __builtin_amdgcn_mfma_f32_16x16x32_bf16(af[m], bq[n], acc[m][n], 0, 0, 0);
    }
    const int rq = (lane >> 4) * 4;
#pragma unroll
    for (int m = 0; m < 4; ++m)
#pragma unroll
        for (int n = 0; n < 4; ++n) {
            int col = n0 + wc * 64 + n * 16 + fr;
#pragma unroll
            for (int r = 0; r < 4; ++r)
                C[(size_t)(m0 + wr * 64 + m * 16 + rq + r) * 32000 + col] = acc[m][n][r];
        }
}

// ---------------------------------------------------------------------------
// Merged prologue conversions: one dispatch, region-switched on blockIdx.
// ---------------------------------------------------------------------------
__global__ __launch_bounds__(256) void prep_k(
    const float* __restrict__ img, const float* __restrict__ Whh,
    const float* __restrict__ Whid, const float* __restrict__ Whead,
    const int* __restrict__ tok, const float* __restrict__ embed,
    const float* __restrict__ bih, const float* __restrict__ bhh,
    u16* __restrict__ img_bf, u16* __restrict__ Whh_bf,
    u16* __restrict__ Whid_bf, u16* __restrict__ Whead_bf,
    u16* __restrict__ emb_bf, float* __restrict__ bsum)
{
    const int bid = blockIdx.x;
    if (bid < 25088) {                       // img cvt: 6,422,528 float4
        int i = bid * 256 + threadIdx.x;
        float4 v = ((const float4*)img)[i];
        ushort4 o; o.x = f2bu(v.x); o.y = f2bu(v.y); o.z = f2bu(v.z); o.w = f2bu(v.w);
        ((ushort4*)img_bf)[i] = o;
    } else if (bid < 29184) {                // Whh cvt
        int i = (bid - 25088) * 256 + threadIdx.x;
        float4 v = ((const float4*)Whh)[i];
        ushort4 o; o.x = f2bu(v.x); o.y = f2bu(v.y); o.z = f2bu(v.z); o.w = f2bu(v.w);
        ((ushort4*)Whh_bf)[i] = o;
    } else if (bid < 29440) {                // Whid cvt
        int i = (bid - 29184) * 256 + threadIdx.x;
        float4 v = ((const float4*)Whid)[i];
        ushort4 o; o.x = f2bu(v.x); o.y = f2bu(v.y); o.z = f2bu(v.z); o.w = f2bu(v.w);
        ((ushort4*)Whid_bf)[i] = o;
    } else if (bid < 61440) {                // Whead cvt
        int i = (bid - 29440) * 256 + threadIdx.x;
        float4 v = ((const float4*)Whead)[i];
        ushort4 o; o.x = f2bu(v.x); o.y = f2bu(v.y); o.z = f2bu(v.z); o.w = f2bu(v.w);
        ((ushort4*)Whead_bf)[i] = o;
    } else if (bid < 65536) {                // emb gather, rows [t][b]
        int id = (bid - 61440) * 256 + threadIdx.x;
        int row = id >> 9, e = id & 511;
        int t = row >> 6, b = row & 63;
        int tk = tok[b * 32 + t];
        emb_bf[(size_t)row * 512 + e] = f2bu(embed[(size_t)tk * 512 + e]);
    } else {                                 // bias sum (16 blocks)
        int i = (bid - 65536) * 256 + threadIdx.x;
        bsum[i] = bih[i] + bhh[i];
    }
}

// Fragment-pack gates weights: Wpk[bid][i][lane][8], i = K-iter (0..95).
__global__ __launch_bounds__(256) void pack_w(const u16* __restrict__ Wic,
                                              const u16* __restrict__ Whh,
                                              u16* __restrict__ Wpk)
{
    const int bid = blockIdx.y;
    const int t2 = blockIdx.x * 256 + threadIdx.x;   // 6144 = 96*64
    const int i = t2 >> 6, lane = t2 & 63;
    const int fr = lane & 15, kq = (lane >> 4) * 8;
    const int grow = ((fr >> 2) << 10) + bid * 4 + (fr & 3);
    const int k0 = i * 32;
    int4 v;
    if (k0 < 2048) v = *(const int4*)&Wic[(size_t)grow * 2048 + k0 + kq];
    else           v = *(const int4*)&Whh[(size_t)grow * 1024 + (k0 - 2048) + kq];
    *(int4*)&Wpk[((size_t)bid * 6144 + t2) * 8] = v;
}

// mean over n of img_bf
__global__ __launch_bounds__(256) void mean_k(const u16* __restrict__ img_bf, float* __restrict__ gT)
{
    int id = blockIdx.x * 256 + threadIdx.x;   // 65536
    int b = id >> 10;
    int d = (id & 1023) * 2;
    const u16* base = img_bf + (size_t)b * 196 * 2048 + d;
    float s0 = 0.f, s1 = 0.f;
#pragma unroll 4
    for (int n = 0; n < 196; ++n) {
        ushort2 v = *(const ushort2*)(base + (size_t)n * 2048);
        s0 += b2f(v.x);
        s1 += b2f(v.y);
    }
    gT[(d + 0) * 64 + b] = s0 * (1.f / 196.f);
    gT[(d + 1) * 64 + b] = s1 * (1.f / 196.f);
}

__global__ __launch_bounds__(256) void h0c0(const float* __restrict__ gT,
                                            const float* __restrict__ Wh0, const float* __restrict__ bh0,
                                            const float* __restrict__ Wc0, const float* __restrict__ bc0,
                                            float* __restrict__ c, u16* __restrict__ h0)
{
    int id = blockIdx.x * 256 + threadIdx.x;
    int b = id & 63, n = id >> 6;
    const float4* Wh = (const float4*)&Wh0[(size_t)n * 2048];
    const float4* Wc = (const float4*)&Wc0[(size_t)n * 2048];
    float s0 = 0.f, s1 = 0.f;
#pragma unroll 4
    for (int k4 = 0; k4 < 512; ++k4) {
        float4 wh = Wh[k4], wc = Wc[k4];
        float g0 = gT[(k4 * 4 + 0) * 64 + b];
        float g1 = gT[(k4 * 4 + 1) * 64 + b];
        float g2 = gT[(k4 * 4 + 2) * 64 + b];
        float g3 = gT[(k4 * 4 + 3) * 64 + b];
        s0 += wh.x * g0 + wh.y * g1 + wh.z * g2 + wh.w * g3;
        s1 += wc.x * g0 + wc.y * g1 + wc.z * g2 + wc.w * g3;
    }
    c[b * 1024 + n] = fast_tanh(s1 + bc0[n]);
    h0[(size_t)b * 1024 + n] = f2bu(fast_tanh(s0 + bh0[n]));
}

// ---------------------------------------------------------------------------
// Per-step kernels — 512 threads (8 waves) for 2 waves/SIMD latency hiding.
// ---------------------------------------------------------------------------

// ph_all[b][a] = h @ W_hid^T. grid 16 blocks x 16 a-cols, 8-wave K-split 128.
__global__ __launch_bounds__(512) void ph_k(const u16* __restrict__ hb,      // [64][1024]
                                            const u16* __restrict__ Whid_bf, // [256][1024]
                                            float* __restrict__ ph_all)      // [64][256]
{
    const int tid = threadIdx.x, lane = tid & 63, wave = tid >> 6;  // 0..7
    const int fr = lane & 15, kq = (lane >> 4) * 8, rq = (lane >> 4) * 4;
    const int a0 = blockIdx.x * 16;
    __shared__ float red[8][64][16];
    f32x4 acc[4];
#pragma unroll
    for (int m = 0; m < 4; ++m) acc[m] = (f32x4){0.f, 0.f, 0.f, 0.f};
#pragma unroll
    for (int kk = 0; kk < 128; kk += 32) {
        const int k0 = wave * 128 + kk;
        bf16x8 bq = *(const bf16x8*)&Whid_bf[(size_t)(a0 + fr) * 1024 + k0 + kq];
#pragma unroll
        for (int m = 0; m < 4; ++m) {
            bf16x8 af = *(const bf16x8*)&hb[(size_t)(m * 16 + fr) * 1024 + k0 + kq];
            acc[m] = __builtin_amdgcn_mfma_f32_16x16x32_bf16(af, bq, acc[m], 0, 0, 0);
        }
    }
#pragma unroll
    for (int m = 0; m < 4; ++m)
#pragma unroll
        for (int r = 0; r < 4; ++r)
            red[wave][m * 16 + rq + r][fr] = acc[m][r];
    __syncthreads();
#pragma unroll
    for (int i = 0; i < 2; ++i) {
        const int idx = tid + i * 512;
        const int bb = idx >> 4, a = idx & 15;
        float s = 0.f;
#pragma unroll
        for (int w8 = 0; w8 < 8; ++w8) s += red[w8][bb][a];
        ph_all[bb * 256 + a0 + a] = s;
    }
}

// scores + softmax + ctx quarter. grid 256 = (b, q), 512 threads.
__global__ __launch_bounds__(512) void attn_k(const float* __restrict__ ph_all,  // [64][256]
                                              const float* __restrict__ w_score, // [256]
                                              const u16* __restrict__ proj_bf,   // [64*196][256]
                                              const u16* __restrict__ img_bf,    // [64][196][2048]
                                              u16* __restrict__ ctx_bf)          // [64][2048]
{
    const int b = blockIdx.x >> 2, q = blockIdx.x & 3;
    const int tid = threadIdx.x, lane = tid & 63, wave = tid >> 6;  // 0..7
    __shared__ float ph[256], ws[256], sc[256], red[256];
    __shared__ float part[8][512];
    if (tid < 256) {
        ph[tid] = ph_all[b * 256 + tid];
        ws[tid] = w_score[tid];
        sc[tid] = -1e30f;
    }
    __syncthreads();
    // scores: wave w handles n = w, w+8, ...
    for (int n = wave; n < 196; n += 8) {
        const int a0 = lane * 4;
        ushort4 pv = *(const ushort4*)&proj_bf[((size_t)b * 196 + n) * 256 + a0];
        float s = ws[a0 + 0] * fast_tanh(b2f(pv.x) + ph[a0 + 0])
                + ws[a0 + 1] * fast_tanh(b2f(pv.y) + ph[a0 + 1])
                + ws[a0 + 2] * fast_tanh(b2f(pv.z) + ph[a0 + 2])
                + ws[a0 + 3] * fast_tanh(b2f(pv.w) + ph[a0 + 3]);
#pragma unroll
        for (int off = 32; off; off >>= 1) s += __shfl_xor(s, off, 64);
        if (lane == 0) sc[n] = s;
    }
    __syncthreads();
    // softmax over 196 (first 256 threads run the trees)
    if (tid < 256) red[tid] = sc[tid];
    __syncthreads();
#pragma unroll
    for (int s2 = 128; s2 > 0; s2 >>= 1) {
        if (tid < s2) red[tid] = fmaxf(red[tid], red[tid + s2]);
        __syncthreads();
    }
    const float mx = red[0];
    __syncthreads();
    float e = (tid < 196) ? __expf(sc[tid] - mx) : 0.f;
    if (tid < 256) red[tid] = e;
    __syncthreads();
#pragma unroll
    for (int s2 = 128; s2 > 0; s2 >>= 1) {
        if (tid < s2) red[tid] += red[tid + s2];
        __syncthreads();
    }
    const float inv = __fdividef(1.f, red[0]);
    __syncthreads();
    if (tid < 256) sc[tid] = e * inv;
    __syncthreads();
    // ctx quarter: 512 cols; group gid (64 groups of 8 cols), 8-way n-split
    const int gid = tid >> 3, st = tid & 7;
    const int c0 = q * 512 + gid * 8;
    const u16* base = img_bf + ((size_t)b * 196) * 2048 + c0;
    float a[8];
#pragma unroll
    for (int i = 0; i < 8; ++i) a[i] = 0.f;
    for (int n = st; n < 196; n += 8) {
        bf16x8 v = *(const bf16x8*)(base + (size_t)n * 2048);
        float wgt = sc[n];
#pragma unroll
        for (int i = 0; i < 8; ++i) a[i] += wgt * (float)v[i];
    }
#pragma unroll
    for (int i = 0; i < 8; ++i) part[st][gid * 8 + i] = a[i];
    __syncthreads();
    const int col = tid;
    float v = part[0][col] + part[1][col] + part[2][col] + part[3][col]
            + part[4][col] + part[5][col] + part[6][col] + part[7][col];
    ctx_bf[(size_t)b * 2048 + q * 512 + col] = f2bu(v);
}

// gates MFMA + LSTM pointwise. grid 256 x 512 threads, 8-wave K-split (384).
__global__ __launch_bounds__(512) void gates_k(const u16* __restrict__ ctx_bf,  // [64][2048]
                                               const u16* __restrict__ hb,      // [64][1024]
                                               const u16* __restrict__ Wpk,     // [256][96][64][8]
                                               const float* __restrict__ xg,    // [32][64][4096]
                                               float* __restrict__ cbuf,        // [64][1024]
                                               u16* __restrict__ h_nxt,         // [64][1024]
                                               u16* __restrict__ h_all,         // [2048][1024]
                                               int t)
{
    const int tid = threadIdx.x, lane = tid & 63, wave = tid >> 6;  // 0..7
    const int fr = lane & 15, kq = (lane >> 4) * 8, rq = (lane >> 4) * 4;
    const int hc0 = blockIdx.x * 4;
    const u16* Wblk = Wpk + (size_t)blockIdx.x * 49152 + lane * 8;  // [96][64][8]
    __shared__ float red[8][64][16];

    f32x4 acc[4];
#pragma unroll
    for (int m = 0; m < 4; ++m) acc[m] = (f32x4){0.f, 0.f, 0.f, 0.f};

    // K in [wave*384, wave*384+384): ctx region [0,2048), h region [2048,3072)
    const int kbeg = wave * 384, kend = kbeg + 384;
    const int cend = kend < 2048 ? kend : 2048;
#pragma unroll 4
    for (int k0 = kbeg; k0 < cend; k0 += 32) {
        bf16x8 bq = *(const bf16x8*)&Wblk[(size_t)(k0 >> 5) * 512];
#pragma unroll
        for (int m = 0; m < 4; ++m) {
            bf16x8 af = *(const bf16x8*)&ctx_bf[(size_t)(m * 16 + fr) * 2048 + k0 + kq];
            acc[m] = __builtin_amdgcn_mfma_f32_16x16x32_bf16(af, bq, acc[m], 0, 0, 0);
        }
    }
    const int hbeg = kbeg > 2048 ? kbeg - 2048 : 0;
    const int hend = kend > 2048 ? kend - 2048 : 0;
#pragma unroll 4
    for (int kh = hbeg; kh < hend; kh += 32) {
        bf16x8 bq = *(const bf16x8*)&Wblk[(size_t)((kh + 2048) >> 5) * 512];
#pragma unroll
        for (int m = 0; m < 4; ++m) {
            bf16x8 af = *(const bf16x8*)&hb[(size_t)(m * 16 + fr) * 1024 + kh + kq];
            acc[m] = __builtin_amdgcn_mfma_f32_16x16x32_bf16(af, bq, acc[m], 0, 0, 0);
        }
    }
#pragma unroll
    for (int m = 0; m < 4; ++m)
#pragma unroll
        for (int r = 0; r < 4; ++r)
            red[wave][m * 16 + rq + r][fr] = acc[m][r];
    __syncthreads();

    // pointwise: thread = (batch bb, col j), first 256 threads
    if (tid < 256) {
        const int bb = tid >> 2, j = tid & 3;
        const int col = hc0 + j;
        float G[4];
#pragma unroll
        for (int g = 0; g < 4; ++g) {
            const int f2 = g * 4 + j;
            float s = 0.f;
#pragma unroll
            for (int w8 = 0; w8 < 8; ++w8) s += red[w8][bb][f2];
            G[g] = s + xg[((size_t)t * 64 + bb) * 4096 + g * 1024 + col];
        }
        float ig = fast_sig(G[0]), fg = fast_sig(G[1]);
        float gv = fast_tanh(G[2]), og = fast_sig(G[3]);
        float cp = cbuf[bb * 1024 + col];
        float cn = fg * cp + ig * gv;
        cbuf[bb * 1024 + col] = cn;
        u16 hv = f2bu(og * fast_tanh(cn));
        h_nxt[(size_t)bb * 1024 + col] = hv;
        h_all[((size_t)bb * 32 + t) * 1024 + col] = hv;
    }
}

// ---------------------------------------------------------------------------
extern "C" void kernel_launch(void* const* d_in, const int* in_sizes, int n_in,
                              void* d_out, int out_size, void* d_ws, size_t ws_size,
                              hipStream_t stream)
{
    const float* img     = (const float*)d_in[0];
    const int*   tok     = (const int*)d_in[1];
    const float* embed   = (const float*)d_in[2];
    const float* W_head1 = (const float*)d_in[3];
    const float* W_ih    = (const float*)d_in[4];
    const float* W_hh    = (const float*)d_in[5];
    const float* b_ih    = (const float*)d_in[6];
    const float* b_hh    = (const float*)d_in[7];
    const float* W_head  = (const float*)d_in[8];
    const float* W_img   = (const float*)d_in[9];
    const float* W_hid   = (const float*)d_in[10];
    const float* w_score = (const float*)d_in[11];
    const float* W_h0    = (const float*)d_in[12];
    const float* b_h0    = (const float*)d_in[13];
    const float* W_c0    = (const float*)d_in[14];
    const float* b_c0    = (const float*)d_in[15];
    float* out = (float*)d_out;

    char* w = (char*)d_ws;
    size_t off = 0;
    auto alloc = [&](size_t bytes) { char* p = w + off; off += (bytes + 255) & ~(size_t)255; return p; };

    u16*   Wic      = (u16*)alloc(4096ULL * 2048 * 2);
    u16*   Whh_bf   = (u16*)alloc(4096ULL * 1024 * 2);
    u16*   Wpk      = (u16*)alloc(256ULL * 96 * 64 * 8 * 2);   // 24 MB fragment-packed
    u16*   Whid_bf  = (u16*)alloc(256ULL * 1024 * 2);
    u16*   Whead_bf = (u16*)alloc(32000ULL * 1024 * 2);
    u16*   img_bf   = (u16*)alloc(64ULL * 196 * 2048 * 2);
    float* xg       = (float*)alloc(2048ULL * 4096 * 4);
    u16*   proj_bf  = (u16*)alloc(64ULL * 196 * 256 * 2);
    u16*   emb_bf   = (u16*)alloc(2048ULL * 512 * 2);
    u16*   xe       = (u16*)alloc(2048ULL * 512 * 2);
    float* gT       = (float*)alloc(2048ULL * 64 * 4);
    float* cbuf     = (float*)alloc(64ULL * 1024 * 4);
    u16*   hbuf     = (u16*)alloc(2ULL * 64 * 1024 * 2);
    u16*   ctx_bf   = (u16*)alloc(64ULL * 2048 * 2);
    u16*   h_all    = (u16*)alloc(2048ULL * 1024 * 2);
    float* ph_all   = (float*)alloc(64ULL * 256 * 4);
    float* bsum     = (float*)alloc(4096ULL * 4);
    (void)ws_size; (void)in_sizes; (void)n_in; (void)out_size;

    // ---- prologue (consolidated)
    prep_k<<<dim3(65552), dim3(256), 0, stream>>>(img, W_hh, W_hid, W_head, tok, embed,
                                                  b_ih, b_hh, img_bf, Whh_bf, Whid_bf,
                                                  Whead_bf, emb_bf, bsum);
    mean_k<<<dim3(256), dim3(256), 0, stream>>>(img_bf, gT);
    h0c0<<<dim3(256), dim3(256), 0, stream>>>(gT, W_h0, b_h0, W_c0, b_c0, cbuf, hbuf);

    // xe = emb @ Wa^T (Wa = W_head1[:, :512]); rows [t][b]
    gemm128<false, true, false, true, false><<<dim3(4, 16), dim3(256), 0, stream>>>(
        emb_bf, 512, W_head1, 2560, xe, 512, nullptr, 512);
    // xg = xe @ W_ih^T + (b_ih + b_hh); rows [t][b]
    gemm128<false, true, false, false, true><<<dim3(32, 16), dim3(256), 0, stream>>>(
        xe, 512, W_ih, 512, xg, 4096, bsum, 512);
    // Wic = W_ih @ W_head1[:, 512:]
    gemm128<true, true, true, true, false><<<dim3(16, 32), dim3(256), 0, stream>>>(
        W_ih, 512, W_head1 + 512, 2560, Wic, 2048, nullptr, 512);
    // proj_bf = img_bf @ W_img^T (bf16 out)
    gemm128<false, true, false, true, false><<<dim3(2, 98), dim3(256), 0, stream>>>(
        img_bf, 2048, W_img, 2048, proj_bf, 256, nullptr, 2048);
    // fragment-pack gates weights (needs Wic + Whh_bf)
    pack_w<<<dim3(24, 256), dim3(256), 0, stream>>>(Wic, Whh_bf, Wpk);

    // ---- recurrence: 3 kernels per step, 512 threads each
    for (int t = 0; t < 32; ++t) {
        u16* hb = hbuf + (size_t)(t & 1) * 65536;
        u16* hn = hbuf + (size_t)((t + 1) & 1) * 65536;
        ph_k<<<dim3(16), dim3(512), 0, stream>>>(hb, Whid_bf, ph_all);
        attn_k<<<dim3(256), dim3(512), 0, stream>>>(ph_all, w_score, proj_bf, img_bf, ctx_bf);
        gates_k<<<dim3(256), dim3(512), 0, stream>>>(ctx_bf, hb, Wpk, xg, cbuf, hn, h_all, t);
    }

    // ---- logits: out = h_all @ W_head^T
    gemm_head<<<dim3(4000), dim3(256), 0, stream>>>(h_all, Whead_bf, out);
}

// Round 8
// 2022.633 us; speedup vs baseline: 1.6485x; 1.1331x over previous
//
#include <hip/hip_runtime.h>
#include <stdint.h>

typedef unsigned short u16;
typedef __bf16 bf16x8 __attribute__((ext_vector_type(8)));
typedef float f32x4 __attribute__((ext_vector_type(4)));

#define DEV static __device__ __forceinline__

DEV u16 f2bu(float f) {
    union { float f; unsigned u; } v; v.f = f;
    unsigned r = v.u + 0x7FFFu + ((v.u >> 16) & 1u);
    return (u16)(r >> 16);
}
DEV float b2f(u16 b) {
    union { unsigned u; float f; } v; v.u = ((unsigned)b) << 16;
    return v.f;
}
DEV float fast_tanh(float x) {
    float e = __expf(2.f * x);
    return 1.f - __fdividef(2.f, e + 1.f);
}
DEV float fast_sig(float x) {
    return __fdividef(1.f, 1.f + __expf(-x));
}
DEV void gload_lds(const u16* g, u16* l) {
    __builtin_amdgcn_global_load_lds((const __attribute__((address_space(1))) void*)g,
                                     (__attribute__((address_space(3))) void*)l, 16, 0, 0);
}

// ---------------------------------------------------------------------------
// Generic 128x128 MFMA GEMM (prologue GEMMs), BK=32, 4 waves (2x2).
// ---------------------------------------------------------------------------
template<bool A_F32, bool B_F32, bool B_KXN, bool OUT_BF16, bool BIAS>
__global__ __launch_bounds__(256) void gemm128(
    const void* __restrict__ Ap, int lda,
    const void* __restrict__ Bp, int ldb,
    void* __restrict__ Cp, int ldc,
    const float* __restrict__ bias, int K)
{
    __shared__ u16 As[128 * 40];
    __shared__ u16 Bs[128 * 40];
    const int tid = threadIdx.x;
    const int lane = tid & 63, wave = tid >> 6;
    const int wr = wave >> 1, wc = wave & 1;
    const int m0 = blockIdx.y * 128, n0 = blockIdx.x * 128;

    f32x4 acc[4][4];
#pragma unroll
    for (int m = 0; m < 4; ++m)
#pragma unroll
        for (int n = 0; n < 4; ++n)
            acc[m][n] = (f32x4){0.f, 0.f, 0.f, 0.f};

    for (int k0 = 0; k0 < K; k0 += 32) {
        __syncthreads();
        if (A_F32) {
            const float* A = (const float*)Ap;
#pragma unroll
            for (int i = 0; i < 4; ++i) {
                int c = tid + i * 256;
                int row = c >> 3, kc = (c & 7) * 4;
                float4 v = *(const float4*)&A[(size_t)(m0 + row) * lda + k0 + kc];
                ushort4 o; o.x = f2bu(v.x); o.y = f2bu(v.y); o.z = f2bu(v.z); o.w = f2bu(v.w);
                *(ushort4*)&As[row * 40 + kc] = o;
            }
        } else {
            const u16* A = (const u16*)Ap;
#pragma unroll
            for (int i = 0; i < 2; ++i) {
                int c = tid + i * 256;
                int row = c >> 2, kc = (c & 3) * 8;
                *(int4*)&As[row * 40 + kc] = *(const int4*)&A[(size_t)(m0 + row) * lda + k0 + kc];
            }
        }
        if (B_KXN) {
            const float* B = (const float*)Bp;
#pragma unroll
            for (int i = 0; i < 4; ++i) {
                int c = tid + i * 256;
                int kk = c >> 5, nc = (c & 31) * 4;
                float4 v = *(const float4*)&B[(size_t)(k0 + kk) * ldb + n0 + nc];
                Bs[(nc + 0) * 40 + kk] = f2bu(v.x);
                Bs[(nc + 1) * 40 + kk] = f2bu(v.y);
                Bs[(nc + 2) * 40 + kk] = f2bu(v.z);
                Bs[(nc + 3) * 40 + kk] = f2bu(v.w);
            }
        } else if (B_F32) {
            const float* B = (const float*)Bp;
#pragma unroll
            for (int i = 0; i < 4; ++i) {
                int c = tid + i * 256;
                int row = c >> 3, kc = (c & 7) * 4;
                float4 v = *(const float4*)&B[(size_t)(n0 + row) * ldb + k0 + kc];
                ushort4 o; o.x = f2bu(v.x); o.y = f2bu(v.y); o.z = f2bu(v.z); o.w = f2bu(v.w);
                *(ushort4*)&Bs[row * 40 + kc] = o;
            }
        } else {
            const u16* B = (const u16*)Bp;
#pragma unroll
            for (int i = 0; i < 2; ++i) {
                int c = tid + i * 256;
                int row = c >> 2, kc = (c & 3) * 8;
                *(int4*)&Bs[row * 40 + kc] = *(const int4*)&B[(size_t)(n0 + row) * ldb + k0 + kc];
            }
        }
        __syncthreads();
        const int fr = lane & 15, kq = (lane >> 4) * 8;
        bf16x8 af[4], bq[4];
#pragma unroll
        for (int m = 0; m < 4; ++m)
            af[m] = *(const bf16x8*)&As[(wr * 64 + m * 16 + fr) * 40 + kq];
#pragma unroll
        for (int n = 0; n < 4; ++n)
            bq[n] = *(const bf16x8*)&Bs[(wc * 64 + n * 16 + fr) * 40 + kq];
#pragma unroll
        for (int m = 0; m < 4; ++m)
#pragma unroll
            for (int n = 0; n < 4; ++n)
                acc[m][n] = __builtin_amdgcn_mfma_f32_16x16x32_bf16(af[m], bq[n], acc[m][n], 0, 0, 0);
    }
    const int fr = lane & 15, rq = (lane >> 4) * 4;
#pragma unroll
    for (int m = 0; m < 4; ++m) {
#pragma unroll
        for (int n = 0; n < 4; ++n) {
            int col = n0 + wc * 64 + n * 16 + fr;
            float bv = BIAS ? bias[col] : 0.f;
#pragma unroll
            for (int r = 0; r < 4; ++r) {
                int row = m0 + wr * 64 + m * 16 + rq + r;
                float v = acc[m][n][r] + bv;
                if (OUT_BF16) ((u16*)Cp)[(size_t)row * ldc + col] = f2bu(v);
                else          ((float*)Cp)[(size_t)row * ldc + col] = v;
            }
        }
    }
}

// ---------------------------------------------------------------------------
// Head GEMM: C[2048][32000] = A(bf16 [2048][1024]) @ B(bf16 [32000][1024])^T
// BK=64, both-sides XOR-swizzle (global source slot ^ row, read slot ^ row)
// so ds_read_b128 is 2-way (free) instead of 16-way at 128B row stride.
// ---------------------------------------------------------------------------
__global__ __launch_bounds__(256) void gemm_head(const u16* __restrict__ A,
                                                 const u16* __restrict__ B,
                                                 float* __restrict__ C)
{
    __shared__ u16 As[128 * 64];
    __shared__ u16 Bs[128 * 64];
    const int tid = threadIdx.x, lane = tid & 63, wave = tid >> 6;
    const int wr = wave >> 1, wc = wave & 1;
    int bid = blockIdx.x;                       // 4000 = 8 * 500
    int nb = (bid & 7) * 500 + (bid >> 3);      // XCD-chunked
    const int m0 = (nb & 15) * 128;             // m fastest -> B-panel L2 reuse
    const int n0 = (nb >> 4) * 128;

    f32x4 acc[4][4];
#pragma unroll
    for (int m = 0; m < 4; ++m)
#pragma unroll
        for (int n = 0; n < 4; ++n)
            acc[m][n] = (f32x4){0.f, 0.f, 0.f, 0.f};

    const int srg = lane >> 3;           // row within 8-row group
    const int sslot = lane & 7;          // 16B slot within 128B row
    const int fr = lane & 15, kg = lane >> 4;   // fragment row / k-group

    for (int k0 = 0; k0 < 1024; k0 += 64) {
        __syncthreads();
#pragma unroll
        for (int j = 0; j < 4; ++j) {
            const int rb = (j * 4 + wave) * 8;      // 8-row group base
            const int ra = rb + srg;
            const int ge = (sslot ^ (ra & 7)) * 8;  // pre-swizzled source elem
            gload_lds(&A[(size_t)(m0 + ra) * 1024 + k0 + ge], &As[rb * 64]);
            gload_lds(&B[(size_t)(n0 + ra) * 1024 + k0 + ge], &Bs[rb * 64]);
        }
        __syncthreads();
#pragma unroll
        for (int kk = 0; kk < 2; ++kk) {
            const int sl = kk * 4 + kg;
            bf16x8 af[4], bq[4];
#pragma unroll
            for (int m = 0; m < 4; ++m) {
                const int row = wr * 64 + m * 16 + fr;
                af[m] = *(const bf16x8*)&As[row * 64 + ((sl ^ (row & 7)) << 3)];
            }
#pragma unroll
            for (int n = 0; n < 4; ++n) {
                const int row = wc * 64 + n * 16 + fr;
                bq[n] = *(const bf16x8*)&Bs[row * 64 + ((sl ^ (row & 7)) << 3)];
            }
#pragma unroll
            for (int m = 0; m < 4; ++m)
#pragma unroll
                for (int n = 0; n < 4; ++n)
                    acc[m][n] = __builtin_amdgcn_mfma_f32_16x16x32_bf16(af[m], bq[n], acc[m][n], 0, 0, 0);
        }
    }
    const int rq = kg * 4;
#pragma unroll
    for (int m = 0; m < 4; ++m)
#pragma unroll
        for (int n = 0; n < 4; ++n) {
            int col = n0 + wc * 64 + n * 16 + fr;
#pragma unroll
            for (int r = 0; r < 4; ++r)
                C[(size_t)(m0 + wr * 64 + m * 16 + rq + r) * 32000 + col] = acc[m][n][r];
        }
}

// ---------------------------------------------------------------------------
// Merged prologue conversions: one dispatch, region-switched on blockIdx.
// ---------------------------------------------------------------------------
__global__ __launch_bounds__(256) void prep_k(
    const float* __restrict__ img, const float* __restrict__ Whh,
    const float* __restrict__ Whid, const float* __restrict__ Whead,
    const int* __restrict__ tok, const float* __restrict__ embed,
    const float* __restrict__ bih, const float* __restrict__ bhh,
    u16* __restrict__ img_bf, u16* __restrict__ Whh_bf,
    u16* __restrict__ Whid_bf, u16* __restrict__ Whead_bf,
    u16* __restrict__ emb_bf, float* __restrict__ bsum)
{
    const int bid = blockIdx.x;
    if (bid < 25088) {                       // img cvt
        int i = bid * 256 + threadIdx.x;
        float4 v = ((const float4*)img)[i];
        ushort4 o; o.x = f2bu(v.x); o.y = f2bu(v.y); o.z = f2bu(v.z); o.w = f2bu(v.w);
        ((ushort4*)img_bf)[i] = o;
    } else if (bid < 29184) {                // Whh cvt
        int i = (bid - 25088) * 256 + threadIdx.x;
        float4 v = ((const float4*)Whh)[i];
        ushort4 o; o.x = f2bu(v.x); o.y = f2bu(v.y); o.z = f2bu(v.z); o.w = f2bu(v.w);
        ((ushort4*)Whh_bf)[i] = o;
    } else if (bid < 29440) {                // Whid cvt
        int i = (bid - 29184) * 256 + threadIdx.x;
        float4 v = ((const float4*)Whid)[i];
        ushort4 o; o.x = f2bu(v.x); o.y = f2bu(v.y); o.z = f2bu(v.z); o.w = f2bu(v.w);
        ((ushort4*)Whid_bf)[i] = o;
    } else if (bid < 61440) {                // Whead cvt
        int i = (bid - 29440) * 256 + threadIdx.x;
        float4 v = ((const float4*)Whead)[i];
        ushort4 o; o.x = f2bu(v.x); o.y = f2bu(v.y); o.z = f2bu(v.z); o.w = f2bu(v.w);
        ((ushort4*)Whead_bf)[i] = o;
    } else if (bid < 65536) {                // emb gather, rows [t][b]
        int id = (bid - 61440) * 256 + threadIdx.x;
        int row = id >> 9, e = id & 511;
        int t = row >> 6, b = row & 63;
        int tk = tok[b * 32 + t];
        emb_bf[(size_t)row * 512 + e] = f2bu(embed[(size_t)tk * 512 + e]);
    } else {                                 // bias sum
        int i = (bid - 65536) * 256 + threadIdx.x;
        bsum[i] = bih[i] + bhh[i];
    }
}

// Fragment-pack gates weights: Wpk[bid][i][lane][8], i = K-iter (0..95).
__global__ __launch_bounds__(256) void pack_w(const u16* __restrict__ Wic,
                                              const u16* __restrict__ Whh,
                                              u16* __restrict__ Wpk)
{
    const int bid = blockIdx.y;
    const int t2 = blockIdx.x * 256 + threadIdx.x;   // 6144 = 96*64
    const int i = t2 >> 6, lane = t2 & 63;
    const int fr = lane & 15, kq = (lane >> 4) * 8;
    const int grow = ((fr >> 2) << 10) + bid * 4 + (fr & 3);
    const int k0 = i * 32;
    int4 v;
    if (k0 < 2048) v = *(const int4*)&Wic[(size_t)grow * 2048 + k0 + kq];
    else           v = *(const int4*)&Whh[(size_t)grow * 1024 + (k0 - 2048) + kq];
    *(int4*)&Wpk[((size_t)bid * 6144 + t2) * 8] = v;
}

// mean over n of img_bf
__global__ __launch_bounds__(256) void mean_k(const u16* __restrict__ img_bf, float* __restrict__ gT)
{
    int id = blockIdx.x * 256 + threadIdx.x;   // 65536
    int b = id >> 10;
    int d = (id & 1023) * 2;
    const u16* base = img_bf + (size_t)b * 196 * 2048 + d;
    float s0 = 0.f, s1 = 0.f;
#pragma unroll 4
    for (int n = 0; n < 196; ++n) {
        ushort2 v = *(const ushort2*)(base + (size_t)n * 2048);
        s0 += b2f(v.x);
        s1 += b2f(v.y);
    }
    gT[(d + 0) * 64 + b] = s0 * (1.f / 196.f);
    gT[(d + 1) * 64 + b] = s1 * (1.f / 196.f);
}

__global__ __launch_bounds__(256) void h0c0(const float* __restrict__ gT,
                                            const float* __restrict__ Wh0, const float* __restrict__ bh0,
                                            const float* __restrict__ Wc0, const float* __restrict__ bc0,
                                            float* __restrict__ c, u16* __restrict__ h0)
{
    int id = blockIdx.x * 256 + threadIdx.x;
    int b = id & 63, n = id >> 6;
    const float4* Wh = (const float4*)&Wh0[(size_t)n * 2048];
    const float4* Wc = (const float4*)&Wc0[(size_t)n * 2048];
    float s0 = 0.f, s1 = 0.f;
#pragma unroll 4
    for (int k4 = 0; k4 < 512; ++k4) {
        float4 wh = Wh[k4], wc = Wc[k4];
        float g0 = gT[(k4 * 4 + 0) * 64 + b];
        float g1 = gT[(k4 * 4 + 1) * 64 + b];
        float g2 = gT[(k4 * 4 + 2) * 64 + b];
        float g3 = gT[(k4 * 4 + 3) * 64 + b];
        s0 += wh.x * g0 + wh.y * g1 + wh.z * g2 + wh.w * g3;
        s1 += wc.x * g0 + wc.y * g1 + wc.z * g2 + wc.w * g3;
    }
    c[b * 1024 + n] = fast_tanh(s1 + bc0[n]);
    h0[(size_t)b * 1024 + n] = f2bu(fast_tanh(s0 + bh0[n]));
}

// ---------------------------------------------------------------------------
// Per-step kernels — 4 waves/SIMD occupancy.
// ---------------------------------------------------------------------------

// ph_all[b][a] = h @ W_hid^T. grid 16 blocks x 16 a-cols, 8-wave K-split 128.
__global__ __launch_bounds__(512) void ph_k(const u16* __restrict__ hb,      // [64][1024]
                                            const u16* __restrict__ Whid_bf, // [256][1024]
                                            float* __restrict__ ph_all)      // [64][256]
{
    const int tid = threadIdx.x, lane = tid & 63, wave = tid >> 6;  // 0..7
    const int fr = lane & 15, kq = (lane >> 4) * 8, rq = (lane >> 4) * 4;
    const int a0 = blockIdx.x * 16;
    __shared__ float red[8][64][16];
    f32x4 acc[4];
#pragma unroll
    for (int m = 0; m < 4; ++m) acc[m] = (f32x4){0.f, 0.f, 0.f, 0.f};
#pragma unroll
    for (int kk = 0; kk < 128; kk += 32) {
        const int k0 = wave * 128 + kk;
        bf16x8 bq = *(const bf16x8*)&Whid_bf[(size_t)(a0 + fr) * 1024 + k0 + kq];
#pragma unroll
        for (int m = 0; m < 4; ++m) {
            bf16x8 af = *(const bf16x8*)&hb[(size_t)(m * 16 + fr) * 1024 + k0 + kq];
            acc[m] = __builtin_amdgcn_mfma_f32_16x16x32_bf16(af, bq, acc[m], 0, 0, 0);
        }
    }
#pragma unroll
    for (int m = 0; m < 4; ++m)
#pragma unroll
        for (int r = 0; r < 4; ++r)
            red[wave][m * 16 + rq + r][fr] = acc[m][r];
    __syncthreads();
#pragma unroll
    for (int i = 0; i < 2; ++i) {
        const int idx = tid + i * 512;
        const int bb = idx >> 4, a = idx & 15;
        float s = 0.f;
#pragma unroll
        for (int w8 = 0; w8 < 8; ++w8) s += red[w8][bb][a];
        ph_all[bb * 256 + a0 + a] = s;
    }
}

// scores + softmax + ctx quarter. grid 256 = (b, q), 1024 threads (16 waves).
__global__ __launch_bounds__(1024) void attn_k(const float* __restrict__ ph_all,  // [64][256]
                                               const float* __restrict__ w_score, // [256]
                                               const u16* __restrict__ proj_bf,   // [64*196][256]
                                               const u16* __restrict__ img_bf,    // [64][196][2048]
                                               u16* __restrict__ ctx_bf)          // [64][2048]
{
    const int b = blockIdx.x >> 2, q = blockIdx.x & 3;
    const int tid = threadIdx.x, lane = tid & 63, wave = tid >> 6;  // 0..15
    __shared__ float ph[256], ws[256], sc[256], red[256];
    __shared__ float part[16][512];
    if (tid < 256) {
        ph[tid] = ph_all[b * 256 + tid];
        ws[tid] = w_score[tid];
        sc[tid] = -1e30f;
    }
    __syncthreads();
    // scores: wave w handles n = w, w+16, ...
    for (int n = wave; n < 196; n += 16) {
        const int a0 = lane * 4;
        ushort4 pv = *(const ushort4*)&proj_bf[((size_t)b * 196 + n) * 256 + a0];
        float s = ws[a0 + 0] * fast_tanh(b2f(pv.x) + ph[a0 + 0])
                + ws[a0 + 1] * fast_tanh(b2f(pv.y) + ph[a0 + 1])
                + ws[a0 + 2] * fast_tanh(b2f(pv.z) + ph[a0 + 2])
                + ws[a0 + 3] * fast_tanh(b2f(pv.w) + ph[a0 + 3]);
#pragma unroll
        for (int off = 32; off; off >>= 1) s += __shfl_xor(s, off, 64);
        if (lane == 0) sc[n] = s;
    }
    __syncthreads();
    // softmax over 196
    if (tid < 256) red[tid] = sc[tid];
    __syncthreads();
#pragma unroll
    for (int s2 = 128; s2 > 0; s2 >>= 1) {
        if (tid < s2) red[tid] = fmaxf(red[tid], red[tid + s2]);
        __syncthreads();
    }
    const float mx = red[0];
    __syncthreads();
    float e = (tid < 196) ? __expf(sc[tid] - mx) : 0.f;
    if (tid < 256) red[tid] = e;
    __syncthreads();
#pragma unroll
    for (int s2 = 128; s2 > 0; s2 >>= 1) {
        if (tid < s2) red[tid] += red[tid + s2];
        __syncthreads();
    }
    const float inv = __fdividef(1.f, red[0]);
    __syncthreads();
    if (tid < 256) sc[tid] = e * inv;
    __syncthreads();
    // ctx quarter: 512 cols; group gid (64 groups of 8 cols), 16-way n-split
    const int gid = tid >> 4, st = tid & 15;
    const int c0 = q * 512 + gid * 8;
    const u16* base = img_bf + ((size_t)b * 196) * 2048 + c0;
    float a[8];
#pragma unroll
    for (int i = 0; i < 8; ++i) a[i] = 0.f;
    for (int n = st; n < 196; n += 16) {
        bf16x8 v = *(const bf16x8*)(base + (size_t)n * 2048);
        float wgt = sc[n];
#pragma unroll
        for (int i = 0; i < 8; ++i) a[i] += wgt * (float)v[i];
    }
#pragma unroll
    for (int i = 0; i < 8; ++i) part[st][gid * 8 + i] = a[i];
    __syncthreads();
    if (tid < 512) {
        const int col = tid;
        float v = 0.f;
#pragma unroll
        for (int s16 = 0; s16 < 16; ++s16) v += part[s16][col];
        ctx_bf[(size_t)b * 2048 + q * 512 + col] = f2bu(v);
    }
}

// gates MFMA + LSTM pointwise. grid 256 x 1024 threads, 16-wave K-split (192).
__global__ __launch_bounds__(1024) void gates_k(const u16* __restrict__ ctx_bf,  // [64][2048]
                                                const u16* __restrict__ hb,      // [64][1024]
                                                const u16* __restrict__ Wpk,     // [256][96][64][8]
                                                const float* __restrict__ xg,    // [32][64][4096]
                                                float* __restrict__ cbuf,        // [64][1024]
                                                u16* __restrict__ h_nxt,         // [64][1024]
                                                u16* __restrict__ h_all,         // [2048][1024]
                                                int t)
{
    const int tid = threadIdx.x, lane = tid & 63, wave = tid >> 6;  // 0..15
    const int fr = lane & 15, kq = (lane >> 4) * 8, rq = (lane >> 4) * 4;
    const int hc0 = blockIdx.x * 4;
    const u16* Wblk = Wpk + (size_t)blockIdx.x * 49152 + lane * 8;  // [96][64][8]
    __shared__ float red[16][64][16];

    f32x4 acc[4];
#pragma unroll
    for (int m = 0; m < 4; ++m) acc[m] = (f32x4){0.f, 0.f, 0.f, 0.f};

    // K in [wave*192, wave*192+192): ctx region [0,2048), h region [2048,3072)
    const int kbeg = wave * 192, kend = kbeg + 192;
    const int cend = kend < 2048 ? kend : 2048;
#pragma unroll 2
    for (int k0 = kbeg; k0 < cend; k0 += 32) {
        bf16x8 bq = *(const bf16x8*)&Wblk[(size_t)(k0 >> 5) * 512];
#pragma unroll
        for (int m = 0; m < 4; ++m) {
            bf16x8 af = *(const bf16x8*)&ctx_bf[(size_t)(m * 16 + fr) * 2048 + k0 + kq];
            acc[m] = __builtin_amdgcn_mfma_f32_16x16x32_bf16(af, bq, acc[m], 0, 0, 0);
        }
    }
    const int hbeg = kbeg > 2048 ? kbeg - 2048 : 0;
    const int hend = kend > 2048 ? kend - 2048 : 0;
#pragma unroll 2
    for (int kh = hbeg; kh < hend; kh += 32) {
        bf16x8 bq = *(const bf16x8*)&Wblk[(size_t)((kh + 2048) >> 5) * 512];
#pragma unroll
        for (int m = 0; m < 4; ++m) {
            bf16x8 af = *(const bf16x8*)&hb[(size_t)(m * 16 + fr) * 1024 + kh + kq];
            acc[m] = __builtin_amdgcn_mfma_f32_16x16x32_bf16(af, bq, acc[m], 0, 0, 0);
        }
    }
#pragma unroll
    for (int m = 0; m < 4; ++m)
#pragma unroll
        for (int r = 0; r < 4; ++r)
            red[wave][m * 16 + rq + r][fr] = acc[m][r];
    __syncthreads();

    // pointwise: thread = (batch bb, col j), first 256 threads
    if (tid < 256) {
        const int bb = tid >> 2, j = tid & 3;
        const int col = hc0 + j;
        float G[4];
#pragma unroll
        for (int g = 0; g < 4; ++g) {
            const int f2 = g * 4 + j;
            float s = 0.f;
#pragma unroll
            for (int w16 = 0; w16 < 16; ++w16) s += red[w16][bb][f2];
            G[g] = s + xg[((size_t)t * 64 + bb) * 4096 + g * 1024 + col];
        }
        float ig = fast_sig(G[0]), fg = fast_sig(G[1]);
        float gv = fast_tanh(G[2]), og = fast_sig(G[3]);
        float cp = cbuf[bb * 1024 + col];
        float cn = fg * cp + ig * gv;
        cbuf[bb * 1024 + col] = cn;
        u16 hv = f2bu(og * fast_tanh(cn));
        h_nxt[(size_t)bb * 1024 + col] = hv;
        h_all[((size_t)bb * 32 + t) * 1024 + col] = hv;
    }
}

// ---------------------------------------------------------------------------
extern "C" void kernel_launch(void* const* d_in, const int* in_sizes, int n_in,
                              void* d_out, int out_size, void* d_ws, size_t ws_size,
                              hipStream_t stream)
{
    const float* img     = (const float*)d_in[0];
    const int*   tok     = (const int*)d_in[1];
    const float* embed   = (const float*)d_in[2];
    const float* W_head1 = (const float*)d_in[3];
    const float* W_ih    = (const float*)d_in[4];
    const float* W_hh    = (const float*)d_in[5];
    const float* b_ih    = (const float*)d_in[6];
    const float* b_hh    = (const float*)d_in[7];
    const float* W_head  = (const float*)d_in[8];
    const float* W_img   = (const float*)d_in[9];
    const float* W_hid   = (const float*)d_in[10];
    const float* w_score = (const float*)d_in[11];
    const float* W_h0    = (const float*)d_in[12];
    const float* b_h0    = (const float*)d_in[13];
    const float* W_c0    = (const float*)d_in[14];
    const float* b_c0    = (const float*)d_in[15];
    float* out = (float*)d_out;

    char* w = (char*)d_ws;
    size_t off = 0;
    auto alloc = [&](size_t bytes) { char* p = w + off; off += (bytes + 255) & ~(size_t)255; return p; };

    u16*   Wic      = (u16*)alloc(4096ULL * 2048 * 2);
    u16*   Whh_bf   = (u16*)alloc(4096ULL * 1024 * 2);
    u16*   Wpk      = (u16*)alloc(256ULL * 96 * 64 * 8 * 2);   // 24 MB fragment-packed
    u16*   Whid_bf  = (u16*)alloc(256ULL * 1024 * 2);
    u16*   Whead_bf = (u16*)alloc(32000ULL * 1024 * 2);
    u16*   img_bf   = (u16*)alloc(64ULL * 196 * 2048 * 2);
    float* xg       = (float*)alloc(2048ULL * 4096 * 4);
    u16*   proj_bf  = (u16*)alloc(64ULL * 196 * 256 * 2);
    u16*   emb_bf   = (u16*)alloc(2048ULL * 512 * 2);
    u16*   xe       = (u16*)alloc(2048ULL * 512 * 2);
    float* gT       = (float*)alloc(2048ULL * 64 * 4);
    float* cbuf     = (float*)alloc(64ULL * 1024 * 4);
    u16*   hbuf     = (u16*)alloc(2ULL * 64 * 1024 * 2);
    u16*   ctx_bf   = (u16*)alloc(64ULL * 2048 * 2);
    u16*   h_all    = (u16*)alloc(2048ULL * 1024 * 2);
    float* ph_all   = (float*)alloc(64ULL * 256 * 4);
    float* bsum     = (float*)alloc(4096ULL * 4);
    (void)ws_size; (void)in_sizes; (void)n_in; (void)out_size;

    // ---- prologue (consolidated)
    prep_k<<<dim3(65552), dim3(256), 0, stream>>>(img, W_hh, W_hid, W_head, tok, embed,
                                                  b_ih, b_hh, img_bf, Whh_bf, Whid_bf,
                                                  Whead_bf, emb_bf, bsum);
    mean_k<<<dim3(256), dim3(256), 0, stream>>>(img_bf, gT);
    h0c0<<<dim3(256), dim3(256), 0, stream>>>(gT, W_h0, b_h0, W_c0, b_c0, cbuf, hbuf);

    // xe = emb @ Wa^T (Wa = W_head1[:, :512]); rows [t][b]
    gemm128<false, true, false, true, false><<<dim3(4, 16), dim3(256), 0, stream>>>(
        emb_bf, 512, W_head1, 2560, xe, 512, nullptr, 512);
    // xg = xe @ W_ih^T + (b_ih + b_hh); rows [t][b]
    gemm128<false, true, false, false, true><<<dim3(32, 16), dim3(256), 0, stream>>>(
        xe, 512, W_ih, 512, xg, 4096, bsum, 512);
    // Wic = W_ih @ W_head1[:, 512:]
    gemm128<true, true, true, true, false><<<dim3(16, 32), dim3(256), 0, stream>>>(
        W_ih, 512, W_head1 + 512, 2560, Wic, 2048, nullptr, 512);
    // proj_bf = img_bf @ W_img^T (bf16 out)
    gemm128<false, true, false, true, false><<<dim3(2, 98), dim3(256), 0, stream>>>(
        img_bf, 2048, W_img, 2048, proj_bf, 256, nullptr, 2048);
    // fragment-pack gates weights (needs Wic + Whh_bf)
    pack_w<<<dim3(24, 256), dim3(256), 0, stream>>>(Wic, Whh_bf, Wpk);

    // ---- recurrence: 3 kernels per step
    for (int t = 0; t < 32; ++t) {
        u16* hb = hbuf + (size_t)(t & 1) * 65536;
        u16* hn = hbuf + (size_t)((t + 1) & 1) * 65536;
        ph_k<<<dim3(16), dim3(512), 0, stream>>>(hb, Whid_bf, ph_all);
        attn_k<<<dim3(256), dim3(1024), 0, stream>>>(ph_all, w_score, proj_bf, img_bf, ctx_bf);
        gates_k<<<dim3(256), dim3(1024), 0, stream>>>(ctx_bf, hb, Wpk, xg, cbuf, hn, h_all, t);
    }

    // ---- logits: out = h_all @ W_head^T
    gemm_head<<<dim3(4000), dim3(256), 0, stream>>>(h_all, Whead_bf, out);
}

// Round 9
// 1941.180 us; speedup vs baseline: 1.7177x; 1.0420x over previous
//
#include <hip/hip_runtime.h>
#include <stdint.h>

typedef unsigned short u16;
typedef __bf16 bf16x8 __attribute__((ext_vector_type(8)));
typedef float f32x4 __attribute__((ext_vector_type(4)));

#define DEV static __device__ __forceinline__

DEV u16 f2bu(float f) {
    union { float f; unsigned u; } v; v.f = f;
    unsigned r = v.u + 0x7FFFu + ((v.u >> 16) & 1u);
    return (u16)(r >> 16);
}
DEV float b2f(u16 b) {
    union { unsigned u; float f; } v; v.u = ((unsigned)b) << 16;
    return v.f;
}
DEV float fast_tanh(float x) {
    float e = __expf(2.f * x);
    return 1.f - __fdividef(2.f, e + 1.f);
}
DEV float fast_sig(float x) {
    return __fdividef(1.f, 1.f + __expf(-x));
}
DEV void gload_lds(const u16* g, u16* l) {
    __builtin_amdgcn_global_load_lds((const __attribute__((address_space(1))) void*)g,
                                     (__attribute__((address_space(3))) void*)l, 16, 0, 0);
}

// ---------------------------------------------------------------------------
// Generic 128x128 MFMA GEMM (prologue GEMMs), BK=32, 4 waves (2x2).
// ---------------------------------------------------------------------------
template<bool A_F32, bool B_F32, bool B_KXN, bool OUT_BF16, bool BIAS>
__global__ __launch_bounds__(256) void gemm128(
    const void* __restrict__ Ap, int lda,
    const void* __restrict__ Bp, int ldb,
    void* __restrict__ Cp, int ldc,
    const float* __restrict__ bias, int K)
{
    __shared__ u16 As[128 * 40];
    __shared__ u16 Bs[128 * 40];
    const int tid = threadIdx.x;
    const int lane = tid & 63, wave = tid >> 6;
    const int wr = wave >> 1, wc = wave & 1;
    const int m0 = blockIdx.y * 128, n0 = blockIdx.x * 128;

    f32x4 acc[4][4];
#pragma unroll
    for (int m = 0; m < 4; ++m)
#pragma unroll
        for (int n = 0; n < 4; ++n)
            acc[m][n] = (f32x4){0.f, 0.f, 0.f, 0.f};

    for (int k0 = 0; k0 < K; k0 += 32) {
        __syncthreads();
        if (A_F32) {
            const float* A = (const float*)Ap;
#pragma unroll
            for (int i = 0; i < 4; ++i) {
                int c = tid + i * 256;
                int row = c >> 3, kc = (c & 7) * 4;
                float4 v = *(const float4*)&A[(size_t)(m0 + row) * lda + k0 + kc];
                ushort4 o; o.x = f2bu(v.x); o.y = f2bu(v.y); o.z = f2bu(v.z); o.w = f2bu(v.w);
                *(ushort4*)&As[row * 40 + kc] = o;
            }
        } else {
            const u16* A = (const u16*)Ap;
#pragma unroll
            for (int i = 0; i < 2; ++i) {
                int c = tid + i * 256;
                int row = c >> 2, kc = (c & 3) * 8;
                *(int4*)&As[row * 40 + kc] = *(const int4*)&A[(size_t)(m0 + row) * lda + k0 + kc];
            }
        }
        if (B_KXN) {
            const float* B = (const float*)Bp;
#pragma unroll
            for (int i = 0; i < 4; ++i) {
                int c = tid + i * 256;
                int kk = c >> 5, nc = (c & 31) * 4;
                float4 v = *(const float4*)&B[(size_t)(k0 + kk) * ldb + n0 + nc];
                Bs[(nc + 0) * 40 + kk] = f2bu(v.x);
                Bs[(nc + 1) * 40 + kk] = f2bu(v.y);
                Bs[(nc + 2) * 40 + kk] = f2bu(v.z);
                Bs[(nc + 3) * 40 + kk] = f2bu(v.w);
            }
        } else if (B_F32) {
            const float* B = (const float*)Bp;
#pragma unroll
            for (int i = 0; i < 4; ++i) {
                int c = tid + i * 256;
                int row = c >> 3, kc = (c & 7) * 4;
                float4 v = *(const float4*)&B[(size_t)(n0 + row) * ldb + k0 + kc];
                ushort4 o; o.x = f2bu(v.x); o.y = f2bu(v.y); o.z = f2bu(v.z); o.w = f2bu(v.w);
                *(ushort4*)&Bs[row * 40 + kc] = o;
            }
        } else {
            const u16* B = (const u16*)Bp;
#pragma unroll
            for (int i = 0; i < 2; ++i) {
                int c = tid + i * 256;
                int row = c >> 2, kc = (c & 3) * 8;
                *(int4*)&Bs[row * 40 + kc] = *(const int4*)&B[(size_t)(n0 + row) * ldb + k0 + kc];
            }
        }
        __syncthreads();
        const int fr = lane & 15, kq = (lane >> 4) * 8;
        bf16x8 af[4], bq[4];
#pragma unroll
        for (int m = 0; m < 4; ++m)
            af[m] = *(const bf16x8*)&As[(wr * 64 + m * 16 + fr) * 40 + kq];
#pragma unroll
        for (int n = 0; n < 4; ++n)
            bq[n] = *(const bf16x8*)&Bs[(wc * 64 + n * 16 + fr) * 40 + kq];
#pragma unroll
        for (int m = 0; m < 4; ++m)
#pragma unroll
            for (int n = 0; n < 4; ++n)
                acc[m][n] = __builtin_amdgcn_mfma_f32_16x16x32_bf16(af[m], bq[n], acc[m][n], 0, 0, 0);
    }
    const int fr = lane & 15, rq = (lane >> 4) * 4;
#pragma unroll
    for (int m = 0; m < 4; ++m) {
#pragma unroll
        for (int n = 0; n < 4; ++n) {
            int col = n0 + wc * 64 + n * 16 + fr;
            float bv = BIAS ? bias[col] : 0.f;
#pragma unroll
            for (int r = 0; r < 4; ++r) {
                int row = m0 + wr * 64 + m * 16 + rq + r;
                float v = acc[m][n][r] + bv;
                if (OUT_BF16) ((u16*)Cp)[(size_t)row * ldc + col] = f2bu(v);
                else          ((float*)Cp)[(size_t)row * ldc + col] = v;
            }
        }
    }
}

// ---------------------------------------------------------------------------
// Head GEMM: C[2048][32000] = A(bf16 [2048][1024]) @ B(bf16 [32000][1024])^T
// 128x256 tile, BK=64, 512 threads (8 waves 2x4, 64x64 each),
// both-sides XOR swizzle (proven conflict-free in R8).
// ---------------------------------------------------------------------------
__global__ __launch_bounds__(512, 4) void gemm_head(const u16* __restrict__ A,
                                                    const u16* __restrict__ B,
                                                    float* __restrict__ C)
{
    __shared__ u16 As[128 * 64];
    __shared__ u16 Bs[256 * 64];
    const int tid = threadIdx.x, lane = tid & 63, wave = tid >> 6;  // 0..7
    const int wr = wave >> 2, wc = wave & 3;
    int bid = blockIdx.x;                       // 2000 = 8 * 250
    int nb = (bid & 7) * 250 + (bid >> 3);      // XCD-chunked
    const int m0 = (nb & 15) * 128;             // m fastest -> B-panel L2 reuse
    const int n0 = (nb >> 4) * 256;

    f32x4 acc[4][4];
#pragma unroll
    for (int m = 0; m < 4; ++m)
#pragma unroll
        for (int n = 0; n < 4; ++n)
            acc[m][n] = (f32x4){0.f, 0.f, 0.f, 0.f};

    const int srg = lane >> 3;           // row within 8-row group
    const int sslot = lane & 7;          // 16B slot within 128B row
    const int ge = (sslot ^ srg) * 8;    // pre-swizzled source elem offset
    const int fr = lane & 15, kg = lane >> 4;   // fragment row / k-group

    for (int k0 = 0; k0 < 1024; k0 += 64) {
        __syncthreads();
#pragma unroll
        for (int j = 0; j < 2; ++j) {            // A: 16 groups / 8 waves
            const int g = wave * 2 + j;
            gload_lds(&A[(size_t)(m0 + g * 8 + srg) * 1024 + k0 + ge], &As[g * 8 * 64]);
        }
#pragma unroll
        for (int j = 0; j < 4; ++j) {            // B: 32 groups / 8 waves
            const int g = wave * 4 + j;
            gload_lds(&B[(size_t)(n0 + g * 8 + srg) * 1024 + k0 + ge], &Bs[g * 8 * 64]);
        }
        __syncthreads();
#pragma unroll
        for (int kk = 0; kk < 2; ++kk) {
            const int sl = kk * 4 + kg;
            bf16x8 af[4], bq[4];
#pragma unroll
            for (int m = 0; m < 4; ++m) {
                const int row = wr * 64 + m * 16 + fr;
                af[m] = *(const bf16x8*)&As[row * 64 + ((sl ^ (row & 7)) << 3)];
            }
#pragma unroll
            for (int n = 0; n < 4; ++n) {
                const int row = wc * 64 + n * 16 + fr;
                bq[n] = *(const bf16x8*)&Bs[row * 64 + ((sl ^ (row & 7)) << 3)];
            }
#pragma unroll
            for (int m = 0; m < 4; ++m)
#pragma unroll
                for (int n = 0; n < 4; ++n)
                    acc[m][n] = __builtin_amdgcn_mfma_f32_16x16x32_bf16(af[m], bq[n], acc[m][n], 0, 0, 0);
        }
    }
    const int rq = kg * 4;
#pragma unroll
    for (int m = 0; m < 4; ++m)
#pragma unroll
        for (int n = 0; n < 4; ++n) {
            int col = n0 + wc * 64 + n * 16 + fr;
#pragma unroll
            for (int r = 0; r < 4; ++r)
                C[(size_t)(m0 + wr * 64 + m * 16 + rq + r) * 32000 + col] = acc[m][n][r];
        }
}

// ---------------------------------------------------------------------------
// Merged prologue conversions: one dispatch, region-switched on blockIdx.
// Whid section packs k-major WhidT[kb][a][e] = Whid[a][kb*8+e].
// ---------------------------------------------------------------------------
__global__ __launch_bounds__(256) void prep_k(
    const float* __restrict__ img, const float* __restrict__ Whh,
    const float* __restrict__ Whid, const float* __restrict__ Whead,
    const int* __restrict__ tok, const float* __restrict__ embed,
    const float* __restrict__ bih, const float* __restrict__ bhh,
    u16* __restrict__ img_bf, u16* __restrict__ Whh_bf,
    u16* __restrict__ WhidT, u16* __restrict__ Whead_bf,
    u16* __restrict__ emb_bf, float* __restrict__ bsum)
{
    const int bid = blockIdx.x;
    if (bid < 25088) {                       // img cvt
        int i = bid * 256 + threadIdx.x;
        float4 v = ((const float4*)img)[i];
        ushort4 o; o.x = f2bu(v.x); o.y = f2bu(v.y); o.z = f2bu(v.z); o.w = f2bu(v.w);
        ((ushort4*)img_bf)[i] = o;
    } else if (bid < 29184) {                // Whh cvt
        int i = (bid - 25088) * 256 + threadIdx.x;
        float4 v = ((const float4*)Whh)[i];
        ushort4 o; o.x = f2bu(v.x); o.y = f2bu(v.y); o.z = f2bu(v.z); o.w = f2bu(v.w);
        ((ushort4*)Whh_bf)[i] = o;
    } else if (bid < 29440) {                // WhidT pack: i -> (a, k4)
        int i = (bid - 29184) * 256 + threadIdx.x;   // 65536
        int a = i >> 8, k4 = (i & 255) * 4;
        float4 v = *(const float4*)&Whid[(size_t)a * 1024 + k4];
        ushort4 o; o.x = f2bu(v.x); o.y = f2bu(v.y); o.z = f2bu(v.z); o.w = f2bu(v.w);
        *(ushort4*)&WhidT[(size_t)(k4 >> 3) * 2048 + a * 8 + (k4 & 7)] = o;
    } else if (bid < 61440) {                // Whead cvt
        int i = (bid - 29440) * 256 + threadIdx.x;
        float4 v = ((const float4*)Whead)[i];
        ushort4 o; o.x = f2bu(v.x); o.y = f2bu(v.y); o.z = f2bu(v.z); o.w = f2bu(v.w);
        ((ushort4*)Whead_bf)[i] = o;
    } else if (bid < 65536) {                // emb gather, rows [t][b]
        int id = (bid - 61440) * 256 + threadIdx.x;
        int row = id >> 9, e = id & 511;
        int t = row >> 6, b = row & 63;
        int tk = tok[b * 32 + t];
        emb_bf[(size_t)row * 512 + e] = f2bu(embed[(size_t)tk * 512 + e]);
    } else {                                 // bias sum
        int i = (bid - 65536) * 256 + threadIdx.x;
        bsum[i] = bih[i] + bhh[i];
    }
}

// Fragment-pack gates weights: Wpk[bid][i][lane][8], i = K-iter (0..95).
__global__ __launch_bounds__(256) void pack_w(const u16* __restrict__ Wic,
                                              const u16* __restrict__ Whh,
                                              u16* __restrict__ Wpk)
{
    const int bid = blockIdx.y;
    const int t2 = blockIdx.x * 256 + threadIdx.x;   // 6144 = 96*64
    const int i = t2 >> 6, lane = t2 & 63;
    const int fr = lane & 15, kq = (lane >> 4) * 8;
    const int grow = ((fr >> 2) << 10) + bid * 4 + (fr & 3);
    const int k0 = i * 32;
    int4 v;
    if (k0 < 2048) v = *(const int4*)&Wic[(size_t)grow * 2048 + k0 + kq];
    else           v = *(const int4*)&Whh[(size_t)grow * 1024 + (k0 - 2048) + kq];
    *(int4*)&Wpk[((size_t)bid * 6144 + t2) * 8] = v;
}

// mean over n of img_bf
__global__ __launch_bounds__(256) void mean_k(const u16* __restrict__ img_bf, float* __restrict__ gT)
{
    int id = blockIdx.x * 256 + threadIdx.x;   // 65536
    int b = id >> 10;
    int d = (id & 1023) * 2;
    const u16* base = img_bf + (size_t)b * 196 * 2048 + d;
    float s0 = 0.f, s1 = 0.f;
#pragma unroll 4
    for (int n = 0; n < 196; ++n) {
        ushort2 v = *(const ushort2*)(base + (size_t)n * 2048);
        s0 += b2f(v.x);
        s1 += b2f(v.y);
    }
    gT[(d + 0) * 64 + b] = s0 * (1.f / 196.f);
    gT[(d + 1) * 64 + b] = s1 * (1.f / 196.f);
}

__global__ __launch_bounds__(256) void h0c0(const float* __restrict__ gT,
                                            const float* __restrict__ Wh0, const float* __restrict__ bh0,
                                            const float* __restrict__ Wc0, const float* __restrict__ bc0,
                                            float* __restrict__ c, u16* __restrict__ h0)
{
    int id = blockIdx.x * 256 + threadIdx.x;
    int b = id & 63, n = id >> 6;
    const float4* Wh = (const float4*)&Wh0[(size_t)n * 2048];
    const float4* Wc = (const float4*)&Wc0[(size_t)n * 2048];
    float s0 = 0.f, s1 = 0.f;
#pragma unroll 4
    for (int k4 = 0; k4 < 512; ++k4) {
        float4 wh = Wh[k4], wc = Wc[k4];
        float g0 = gT[(k4 * 4 + 0) * 64 + b];
        float g1 = gT[(k4 * 4 + 1) * 64 + b];
        float g2 = gT[(k4 * 4 + 2) * 64 + b];
        float g3 = gT[(k4 * 4 + 3) * 64 + b];
        s0 += wh.x * g0 + wh.y * g1 + wh.z * g2 + wh.w * g3;
        s1 += wc.x * g0 + wc.y * g1 + wc.z * g2 + wc.w * g3;
    }
    c[b * 1024 + n] = fast_tanh(s1 + bc0[n]);
    h0[(size_t)b * 1024 + n] = f2bu(fast_tanh(s0 + bh0[n]));
}

// ---------------------------------------------------------------------------
// Per-step kernel 1: ph + scores + softmax + ctx quarter. grid 256 = (b,q),
// 1024 threads. ph computed in-block from k-major WhidT (coalesced 16B/lane),
// 4 K-slices x 256 a-cols, LDS reduce.
// ---------------------------------------------------------------------------
__global__ __launch_bounds__(1024) void attn_k(const u16* __restrict__ hb,      // [64][1024]
                                               const u16* __restrict__ WhidT,   // [128][256][8]
                                               const float* __restrict__ w_score,
                                               const u16* __restrict__ proj_bf, // [64*196][256]
                                               const u16* __restrict__ img_bf,  // [64][196][2048]
                                               u16* __restrict__ ctx_bf)        // [64][2048]
{
    const int b = blockIdx.x >> 2, q = blockIdx.x & 3;
    const int tid = threadIdx.x, lane = tid & 63, wave = tid >> 6;  // 0..15
    __shared__ float ph[256], ws[256], sc[256], red[256];
    __shared__ float hsh[1024];
    __shared__ float php[4][256];
    __shared__ float part[16][512];

    if (tid < 256) {
        ws[tid] = w_score[tid];
        sc[tid] = -1e30f;
    }
    hsh[tid] = b2f(hb[(size_t)b * 1024 + tid]);
    __syncthreads();

    // ph[a] = dot(h_b, Whid[a]) : thread (a = tid&255, ks = tid>>8)
    {
        const int a = tid & 255, ks = tid >> 8;
        float s = 0.f;
        const u16* wp = WhidT + a * 8;
#pragma unroll 8
        for (int j = 0; j < 32; ++j) {
            const int kb = ks * 32 + j;
            bf16x8 wv = *(const bf16x8*)(wp + (size_t)kb * 2048);
            const float* hk = &hsh[kb * 8];
#pragma unroll
            for (int i = 0; i < 8; ++i) s += hk[i] * (float)wv[i];
        }
        php[ks][a] = s;
    }
    __syncthreads();
    if (tid < 256) ph[tid] = php[0][tid] + php[1][tid] + php[2][tid] + php[3][tid];
    __syncthreads();

    // scores: wave w handles n = w, w+16, ...
    for (int n = wave; n < 196; n += 16) {
        const int a0 = lane * 4;
        ushort4 pv = *(const ushort4*)&proj_bf[((size_t)b * 196 + n) * 256 + a0];
        float s = ws[a0 + 0] * fast_tanh(b2f(pv.x) + ph[a0 + 0])
                + ws[a0 + 1] * fast_tanh(b2f(pv.y) + ph[a0 + 1])
                + ws[a0 + 2] * fast_tanh(b2f(pv.z) + ph[a0 + 2])
                + ws[a0 + 3] * fast_tanh(b2f(pv.w) + ph[a0 + 3]);
#pragma unroll
        for (int off = 32; off; off >>= 1) s += __shfl_xor(s, off, 64);
        if (lane == 0) sc[n] = s;
    }
    __syncthreads();
    // softmax over 196
    if (tid < 256) red[tid] = sc[tid];
    __syncthreads();
#pragma unroll
    for (int s2 = 128; s2 > 0; s2 >>= 1) {
        if (tid < s2) red[tid] = fmaxf(red[tid], red[tid + s2]);
        __syncthreads();
    }
    const float mx = red[0];
    __syncthreads();
    float e = (tid < 196) ? __expf(sc[tid] - mx) : 0.f;
    if (tid < 256) red[tid] = e;
    __syncthreads();
#pragma unroll
    for (int s2 = 128; s2 > 0; s2 >>= 1) {
        if (tid < s2) red[tid] += red[tid + s2];
        __syncthreads();
    }
    const float inv = __fdividef(1.f, red[0]);
    __syncthreads();
    if (tid < 256) sc[tid] = e * inv;
    __syncthreads();
    // ctx quarter: 512 cols; group gid (64 groups of 8 cols), 16-way n-split
    const int gid = tid >> 4, st = tid & 15;
    const int c0 = q * 512 + gid * 8;
    const u16* base = img_bf + ((size_t)b * 196) * 2048 + c0;
    float a[8];
#pragma unroll
    for (int i = 0; i < 8; ++i) a[i] = 0.f;
    for (int n = st; n < 196; n += 16) {
        bf16x8 v = *(const bf16x8*)(base + (size_t)n * 2048);
        float wgt = sc[n];
#pragma unroll
        for (int i = 0; i < 8; ++i) a[i] += wgt * (float)v[i];
    }
#pragma unroll
    for (int i = 0; i < 8; ++i) part[st][gid * 8 + i] = a[i];
    __syncthreads();
    if (tid < 512) {
        const int col = tid;
        float v = 0.f;
#pragma unroll
        for (int s16 = 0; s16 < 16; ++s16) v += part[s16][col];
        ctx_bf[(size_t)b * 2048 + q * 512 + col] = f2bu(v);
    }
}

// ---------------------------------------------------------------------------
// Per-step kernel 2: gates MFMA + LSTM pointwise. grid 256 x 1024 threads,
// 16-wave K-split (192 each).
// ---------------------------------------------------------------------------
__global__ __launch_bounds__(1024) void gates_k(const u16* __restrict__ ctx_bf,  // [64][2048]
                                                const u16* __restrict__ hb,      // [64][1024]
                                                const u16* __restrict__ Wpk,     // [256][96][64][8]
                                                const float* __restrict__ xg,    // [32][64][4096]
                                                float* __restrict__ cbuf,        // [64][1024]
                                                u16* __restrict__ h_nxt,         // [64][1024]
                                                u16* __restrict__ h_all,         // [2048][1024]
                                                int t)
{
    const int tid = threadIdx.x, lane = tid & 63, wave = tid >> 6;  // 0..15
    const int fr = lane & 15, kq = (lane >> 4) * 8, rq = (lane >> 4) * 4;
    const int hc0 = blockIdx.x * 4;
    const u16* Wblk = Wpk + (size_t)blockIdx.x * 49152 + lane * 8;  // [96][64][8]
    __shared__ float red[16][64][16];

    f32x4 acc[4];
#pragma unroll
    for (int m = 0; m < 4; ++m) acc[m] = (f32x4){0.f, 0.f, 0.f, 0.f};

    // K in [wave*192, wave*192+192): ctx region [0,2048), h region [2048,3072)
    const int kbeg = wave * 192, kend = kbeg + 192;
    const int cend = kend < 2048 ? kend : 2048;
#pragma unroll 2
    for (int k0 = kbeg; k0 < cend; k0 += 32) {
        bf16x8 bq = *(const bf16x8*)&Wblk[(size_t)(k0 >> 5) * 512];
#pragma unroll
        for (int m = 0; m < 4; ++m) {
            bf16x8 af = *(const bf16x8*)&ctx_bf[(size_t)(m * 16 + fr) * 2048 + k0 + kq];
            acc[m] = __builtin_amdgcn_mfma_f32_16x16x32_bf16(af, bq, acc[m], 0, 0, 0);
        }
    }
    const int hbeg = kbeg > 2048 ? kbeg - 2048 : 0;
    const int hend = kend > 2048 ? kend - 2048 : 0;
#pragma unroll 2
    for (int kh = hbeg; kh < hend; kh += 32) {
        bf16x8 bq = *(const bf16x8*)&Wblk[(size_t)((kh + 2048) >> 5) * 512];
#pragma unroll
        for (int m = 0; m < 4; ++m) {
            bf16x8 af = *(const bf16x8*)&hb[(size_t)(m * 16 + fr) * 1024 + kh + kq];
            acc[m] = __builtin_amdgcn_mfma_f32_16x16x32_bf16(af, bq, acc[m], 0, 0, 0);
        }
    }
#pragma unroll
    for (int m = 0; m < 4; ++m)
#pragma unroll
        for (int r = 0; r < 4; ++r)
            red[wave][m * 16 + rq + r][fr] = acc[m][r];
    __syncthreads();

    // pointwise: thread = (batch bb, col j), first 256 threads
    if (tid < 256) {
        const int bb = tid >> 2, j = tid & 3;
        const int col = hc0 + j;
        float G[4];
#pragma unroll
        for (int g = 0; g < 4; ++g) {
            const int f2 = g * 4 + j;
            float s = 0.f;
#pragma unroll
            for (int w16 = 0; w16 < 16; ++w16) s += red[w16][bb][f2];
            G[g] = s + xg[((size_t)t * 64 + bb) * 4096 + g * 1024 + col];
        }
        float ig = fast_sig(G[0]), fg = fast_sig(G[1]);
        float gv = fast_tanh(G[2]), og = fast_sig(G[3]);
        float cp = cbuf[bb * 1024 + col];
        float cn = fg * cp + ig * gv;
        cbuf[bb * 1024 + col] = cn;
        u16 hv = f2bu(og * fast_tanh(cn));
        h_nxt[(size_t)bb * 1024 + col] = hv;
        h_all[((size_t)bb * 32 + t) * 1024 + col] = hv;
    }
}

// ---------------------------------------------------------------------------
extern "C" void kernel_launch(void* const* d_in, const int* in_sizes, int n_in,
                              void* d_out, int out_size, void* d_ws, size_t ws_size,
                              hipStream_t stream)
{
    const float* img     = (const float*)d_in[0];
    const int*   tok     = (const int*)d_in[1];
    const float* embed   = (const float*)d_in[2];
    const float* W_head1 = (const float*)d_in[3];
    const float* W_ih    = (const float*)d_in[4];
    const float* W_hh    = (const float*)d_in[5];
    const float* b_ih    = (const float*)d_in[6];
    const float* b_hh    = (const float*)d_in[7];
    const float* W_head  = (const float*)d_in[8];
    const float* W_img   = (const float*)d_in[9];
    const float* W_hid   = (const float*)d_in[10];
    const float* w_score = (const float*)d_in[11];
    const float* W_h0    = (const float*)d_in[12];
    const float* b_h0    = (const float*)d_in[13];
    const float* W_c0    = (const float*)d_in[14];
    const float* b_c0    = (const float*)d_in[15];
    float* out = (float*)d_out;

    char* w = (char*)d_ws;
    size_t off = 0;
    auto alloc = [&](size_t bytes) { char* p = w + off; off += (bytes + 255) & ~(size_t)255; return p; };

    u16*   Wic      = (u16*)alloc(4096ULL * 2048 * 2);
    u16*   Whh_bf   = (u16*)alloc(4096ULL * 1024 * 2);
    u16*   Wpk      = (u16*)alloc(256ULL * 96 * 64 * 8 * 2);   // 24 MB fragment-packed
    u16*   WhidT    = (u16*)alloc(256ULL * 1024 * 2);
    u16*   Whead_bf = (u16*)alloc(32000ULL * 1024 * 2);
    u16*   img_bf   = (u16*)alloc(64ULL * 196 * 2048 * 2);
    float* xg       = (float*)alloc(2048ULL * 4096 * 4);
    u16*   proj_bf  = (u16*)alloc(64ULL * 196 * 256 * 2);
    u16*   emb_bf   = (u16*)alloc(2048ULL * 512 * 2);
    u16*   xe       = (u16*)alloc(2048ULL * 512 * 2);
    float* gT       = (float*)alloc(2048ULL * 64 * 4);
    float* cbuf     = (float*)alloc(64ULL * 1024 * 4);
    u16*   hbuf     = (u16*)alloc(2ULL * 64 * 1024 * 2);
    u16*   ctx_bf   = (u16*)alloc(64ULL * 2048 * 2);
    u16*   h_all    = (u16*)alloc(2048ULL * 1024 * 2);
    float* bsum     = (float*)alloc(4096ULL * 4);
    (void)ws_size; (void)in_sizes; (void)n_in; (void)out_size;

    // ---- prologue (consolidated)
    prep_k<<<dim3(65552), dim3(256), 0, stream>>>(img, W_hh, W_hid, W_head, tok, embed,
                                                  b_ih, b_hh, img_bf, Whh_bf, WhidT,
                                                  Whead_bf, emb_bf, bsum);
    mean_k<<<dim3(256), dim3(256), 0, stream>>>(img_bf, gT);
    h0c0<<<dim3(256), dim3(256), 0, stream>>>(gT, W_h0, b_h0, W_c0, b_c0, cbuf, hbuf);

    // xe = emb @ Wa^T (Wa = W_head1[:, :512]); rows [t][b]
    gemm128<false, true, false, true, false><<<dim3(4, 16), dim3(256), 0, stream>>>(
        emb_bf, 512, W_head1, 2560, xe, 512, nullptr, 512);
    // xg = xe @ W_ih^T + (b_ih + b_hh); rows [t][b]
    gemm128<false, true, false, false, true><<<dim3(32, 16), dim3(256), 0, stream>>>(
        xe, 512, W_ih, 512, xg, 4096, bsum, 512);
    // Wic = W_ih @ W_head1[:, 512:]
    gemm128<true, true, true, true, false><<<dim3(16, 32), dim3(256), 0, stream>>>(
        W_ih, 512, W_head1 + 512, 2560, Wic, 2048, nullptr, 512);
    // proj_bf = img_bf @ W_img^T (bf16 out)
    gemm128<false, true, false, true, false><<<dim3(2, 98), dim3(256), 0, stream>>>(
        img_bf, 2048, W_img, 2048, proj_bf, 256, nullptr, 2048);
    // fragment-pack gates weights (needs Wic + Whh_bf)
    pack_w<<<dim3(24, 256), dim3(256), 0, stream>>>(Wic, Whh_bf, Wpk);

    // ---- recurrence: 2 kernels per step
    for (int t = 0; t < 32; ++t) {
        u16* hb = hbuf + (size_t)(t & 1) * 65536;
        u16* hn = hbuf + (size_t)((t + 1) & 1) * 65536;
        attn_k<<<dim3(256), dim3(1024), 0, stream>>>(hb, WhidT, w_score, proj_bf, img_bf, ctx_bf);
        gates_k<<<dim3(256), dim3(1024), 0, stream>>>(ctx_bf, hb, Wpk, xg, cbuf, hn, h_all, t);
    }

    // ---- logits: out = h_all @ W_head^T
    gemm_head<<<dim3(2000), dim3(512), 0, stream>>>(h_all, Whead_bf, out);
}